// Round 9
// baseline (6810.519 us; speedup 1.0000x reference)
//
#include <hip/hip_runtime.h>
#include <hip/hip_bf16.h>
#include <math.h>

typedef __bf16 bf16x8 __attribute__((ext_vector_type(8)));
typedef float f32x4 __attribute__((ext_vector_type(4)));
typedef unsigned short ushort;

#define QOFF ((size_t)96*16384)   // hi->lo plane offset for q/k/v split pairs

__device__ __forceinline__ float siluf(float x){ return x / (1.0f + expf(-x)); }
__device__ __forceinline__ float geluf(float x){ return 0.5f*x*(1.0f+erff(x*0.70710678118654752f)); }
__device__ __forceinline__ float bf2f(ushort h){
  union { unsigned int u; float f; } z; z.u = ((unsigned int)h) << 16; return z.f;
}
// exact truncation split: f = hi + lo with hi,lo bf16 (trunc)
__device__ __forceinline__ void split1(float f, ushort& hi, ushort& lo){
  union { float f; unsigned int u; } a; a.f = f;
  unsigned int h = a.u & 0xffff0000u;
  hi = (ushort)(h >> 16);
  union { unsigned int u; float f; } hf; hf.u = h;
  union { float f; unsigned int u; } l; l.f = f - hf.f;
  lo = (ushort)(l.u >> 16);
}
__device__ __forceinline__ ushort f2bf(float f){
  union { float f; unsigned int u; } v; v.f = f;
  unsigned int r = v.u + 0x7fffu + ((v.u >> 16) & 1u);
  return (ushort)(r >> 16);
}

// ---------------- weight transpose+split: src fp32 [K][N] -> dstH/dstL bf16 [N][K], z = plane
__global__ __launch_bounds__(256) void k_wsplit(const float* __restrict__ src,
    ushort* __restrict__ dstH, ushort* __restrict__ dstL, int K, int N){
  __shared__ float lds[64][65];
  int n0 = blockIdx.x*64, k0 = blockIdx.y*64;
  size_t zb = (size_t)blockIdx.z*K*N;
  int tid = threadIdx.x;
  int c = tid & 63, rq = tid >> 6;
  #pragma unroll
  for (int i = 0; i < 16; i++){
    int kk = i*4 + rq;
    lds[kk][c] = src[zb + (size_t)(k0+kk)*N + n0 + c];
  }
  __syncthreads();
  #pragma unroll
  for (int i = 0; i < 16; i++){
    int nn = i*4 + rq;
    float v = lds[c][nn];
    ushort h, l; split1(v, h, l);
    dstH[zb + (size_t)(n0+nn)*K + k0 + c] = h;
    dstL[zb + (size_t)(n0+nn)*K + k0 + c] = l;
  }
}

// ---------------- patchify -> split bf16 (T,768), feature order (c,ph,pw)
__global__ void k_patchify(const float* __restrict__ x,
                           ushort* __restrict__ xh, ushort* __restrict__ xl){
  int idx = blockIdx.x*256 + threadIdx.x;
  int t = idx / 768, f = idx % 768;
  int b = t >> 8, n = t & 255;
  int gh = n >> 4, gw = n & 15;
  int c = f >> 8, r = f & 255;
  int ph = r >> 4, pw = r & 15;
  float v = x[(((size_t)(b*3 + c)*256) + gh*16 + ph)*256 + gw*16 + pw];
  ushort h, l; split1(v, h, l);
  xh[idx] = h; xl[idx] = l;
}

// ---------------- timestep + task/modality conditioning -> c (8,768)
__global__ __launch_bounds__(256) void k_cond(const float* __restrict__ t,
    const int* __restrict__ task_id, const int* __restrict__ mod_id,
    const float* __restrict__ t1w, const float* __restrict__ t1b,
    const float* __restrict__ t2w, const float* __restrict__ t2b,
    const float* __restrict__ task_tab, const float* __restrict__ mod_tab,
    float* __restrict__ c){
  __shared__ float te[256];
  __shared__ float tm[768];
  int b = blockIdx.x, tid = threadIdx.x;
  float tv = t[b];
  int i = tid & 127;
  float freq = expf(-9.210340371976184f * (float)i / 128.0f);
  float arg = tv * freq;
  te[tid] = (tid < 128) ? cosf(arg) : sinf(arg);
  __syncthreads();
  for (int d = tid; d < 768; d += 256){
    float acc = t1b[d];
    for (int k = 0; k < 256; k++) acc += te[k]*t1w[k*768+d];
    tm[d] = siluf(acc);
  }
  __syncthreads();
  for (int d = tid; d < 768; d += 256){
    float acc = t2b[d];
    for (int k = 0; k < 768; k++) acc += tm[k]*t2w[k*768+d];
    c[b*768+d] = acc + task_tab[task_id[b]*768+d] + mod_tab[mod_id[b]*768+d];
  }
}

// ---------------- out[b][n] = bias[n] + sum_k silu(c[b][k]) * W[k][n]
__global__ __launch_bounds__(256) void k_mod(const float* __restrict__ c,
    const float* __restrict__ W, const float* __restrict__ bias,
    float* __restrict__ out, int N){
  __shared__ float sc[768];
  int b = blockIdx.y, tid = threadIdx.x;
  for (int k = tid; k < 768; k += 256) sc[k] = siluf(c[b*768+k]);
  __syncthreads();
  int n = blockIdx.x*256 + tid;
  float acc = bias[n];
  for (int k = 0; k < 768; k++) acc += sc[k]*W[(size_t)k*N + n];
  out[(size_t)b*N + n] = acc;
}

// ---------------- rmsnorm + modulate -> split bf16 pair
__global__ __launch_bounds__(256) void k_rms_mod(const float* __restrict__ x,
    ushort* __restrict__ oh, ushort* __restrict__ ol,
    const float* __restrict__ w,
    const float* __restrict__ shift, const float* __restrict__ scale, int mstride){
  __shared__ float red[256];
  int t = blockIdx.x, tid = threadIdx.x;
  float v0 = x[t*768 + tid], v1 = x[t*768 + 256 + tid], v2 = x[t*768 + 512 + tid];
  red[tid] = v0*v0 + v1*v1 + v2*v2;
  __syncthreads();
  for (int s2 = 128; s2 > 0; s2 >>= 1){ if (tid < s2) red[tid] += red[tid+s2]; __syncthreads(); }
  float r = rsqrtf(red[0]/768.0f + 1e-6f);
  int b = t >> 8;
  const float* sh = shift + (size_t)b*mstride;
  const float* scp = scale + (size_t)b*mstride;
  float o0 = v0*r*w[tid]    *(1.0f+scp[tid])     + sh[tid];
  float o1 = v1*r*w[tid+256]*(1.0f+scp[tid+256]) + sh[tid+256];
  float o2 = v2*r*w[tid+512]*(1.0f+scp[tid+512]) + sh[tid+512];
  ushort h, l;
  split1(o0, h, l); oh[t*768 + tid]       = h; ol[t*768 + tid]       = l;
  split1(o1, h, l); oh[t*768 + 256 + tid] = h; ol[t*768 + 256 + tid] = l;
  split1(o2, h, l); oh[t*768 + 512 + tid] = h; ol[t*768 + 512 + tid] = l;
}

// ---------------- q/k head-rms + 2D RoPE on split pairs; fp32 math; final bf16 into hi plane
__global__ __launch_bounds__(256) void k_qkv_prep(ushort* __restrict__ qp, ushort* __restrict__ kp,
    const float* __restrict__ qnw, const float* __restrict__ knw){
  int t = blockIdx.x;
  int wid = threadIdx.x >> 6, lane = threadIdx.x & 63;
  int n = t & 255, b = t >> 8;
  float phc = (float)(n >> 4), pwc = (float)(n & 15);
  int j = (lane & 31) >> 1;
  float freq = expf(-9.210340371976184f * (float)j / 16.0f);
  float ang = ((lane < 32) ? phc : pwc) * freq;
  float ca = cosf(ang), sa = sinf(ang);
  for (int r = wid; r < 24; r += 4){
    int isK = (r >= 12);
    int h = isK ? r - 12 : r;
    ushort* p = (isK ? kp : qp) + ((size_t)(b*12 + h))*16384 + n*64 + lane;
    float v = bf2f(p[0]) + bf2f(p[QOFF]);
    float ss = v*v;
    #pragma unroll
    for (int off = 32; off; off >>= 1) ss += __shfl_xor(ss, off);
    float rr = rsqrtf(ss/64.0f + 1e-6f);
    float w = isK ? knw[lane] : qnw[lane];
    float xn = v*rr*w;
    float partner = __shfl_xor(xn, 1);
    float xr = (lane & 1) ? partner : -partner;
    float res = xn*ca + xr*sa;
    if (!isK) res *= 0.125f;
    *p = f2bf(res);
  }
}

// ---------------- V transpose: v pair [bh][n][d] (hi+lo) -> vt bf16 [bh][d][n]
__global__ __launch_bounds__(256) void k_vtrans(const ushort* __restrict__ vp,
                                                ushort* __restrict__ vt){
  __shared__ float lds[64][65];
  int bh = blockIdx.x;
  int tid = threadIdx.x;
  for (int p = 0; p < 4; p++){
    int n0 = p*64;
    __syncthreads();
    #pragma unroll
    for (int i = 0; i < 16; i++){
      int tt = i*4 + (tid>>6);
      int d = tid&63;
      size_t idx = (size_t)bh*16384 + (n0 + tt)*64 + d;
      lds[tt][d] = bf2f(vp[idx]) + bf2f(vp[idx + QOFF]);
    }
    __syncthreads();
    #pragma unroll
    for (int i = 0; i < 16; i++){
      int d = i*4 + (tid>>6);
      int nn = tid&63;
      vt[(size_t)bh*16384 + d*256 + n0 + nn] = f2bf(lds[nn][d]);
    }
  }
}

// ---------------- fused MFMA attention (r5-proven structure)
#define KP 72
#define VP 264
__global__ __launch_bounds__(256) void k_fattn(
    const ushort* __restrict__ qb, const ushort* __restrict__ kb,
    const ushort* __restrict__ vt,
    ushort* __restrict__ oh, ushort* __restrict__ ol){
  __shared__ ushort ksh[256*KP];
  __shared__ ushort vsh[64*VP];
  __shared__ ushort psh[4][16*VP];
  int qt = blockIdx.x, bh = blockIdx.y;
  int b = bh/12, h = bh%12;
  int tid = threadIdx.x;
  #pragma unroll
  for (int it = 0; it < 8; it++){
    int idx = it*256 + tid;
    int row = idx >> 3, ch = idx & 7;
    *(uint4*)&ksh[row*KP + ch*8] = *(const uint4*)&kb[(size_t)bh*16384 + row*64 + ch*8];
  }
  #pragma unroll
  for (int it = 0; it < 8; it++){
    int idx = it*256 + tid;
    int row = idx >> 5, ch = idx & 31;
    *(uint4*)&vsh[row*VP + ch*8] = *(const uint4*)&vt[(size_t)bh*16384 + row*256 + ch*8];
  }
  __syncthreads();
  int lane = tid & 63, w = tid >> 6;
  int lr = lane & 15, lg = lane >> 4;
  int q0 = qt*64 + w*16;
  bf16x8 af0 = *(const bf16x8*)&qb[(size_t)bh*16384 + (q0 + lr)*64 + lg*8];
  bf16x8 af1 = *(const bf16x8*)&qb[(size_t)bh*16384 + (q0 + lr)*64 + lg*8 + 32];
  f32x4 s[16];
  #pragma unroll
  for (int nt = 0; nt < 16; nt++){
    f32x4 z = {};
    z = __builtin_amdgcn_mfma_f32_16x16x32_bf16(af0, *(const bf16x8*)&ksh[(nt*16 + lr)*KP + lg*8], z, 0, 0, 0);
    z = __builtin_amdgcn_mfma_f32_16x16x32_bf16(af1, *(const bf16x8*)&ksh[(nt*16 + lr)*KP + lg*8 + 32], z, 0, 0, 0);
    s[nt] = z;
  }
  float inv[4];
  #pragma unroll
  for (int r = 0; r < 4; r++){
    float m = -1e30f;
    #pragma unroll
    for (int nt = 0; nt < 16; nt++) m = fmaxf(m, s[nt][r]);
    #pragma unroll
    for (int off = 1; off < 16; off <<= 1) m = fmaxf(m, __shfl_xor(m, off));
    float sum = 0.f;
    #pragma unroll
    for (int nt = 0; nt < 16; nt++){ float p = expf(s[nt][r] - m); s[nt][r] = p; sum += p; }
    #pragma unroll
    for (int off = 1; off < 16; off <<= 1) sum += __shfl_xor(sum, off);
    inv[r] = 1.0f/sum;
  }
  #pragma unroll
  for (int nt = 0; nt < 16; nt++){
    #pragma unroll
    for (int r = 0; r < 4; r++)
      psh[w][(lg*4 + r)*VP + nt*16 + lr] = f2bf(s[nt][r]);
  }
  __syncthreads();
  f32x4 o[4] = {};
  #pragma unroll
  for (int dt = 0; dt < 4; dt++){
    #pragma unroll
    for (int k0 = 0; k0 < 8; k0++){
      bf16x8 pa = *(const bf16x8*)&psh[w][lr*VP + lg*8 + k0*32];
      bf16x8 bv = *(const bf16x8*)&vsh[(dt*16 + lr)*VP + lg*8 + k0*32];
      o[dt] = __builtin_amdgcn_mfma_f32_16x16x32_bf16(pa, bv, o[dt], 0, 0, 0);
    }
  }
  #pragma unroll
  for (int dt = 0; dt < 4; dt++){
    #pragma unroll
    for (int r = 0; r < 4; r++){
      int token = b*256 + q0 + lg*4 + r;
      int col = h*64 + dt*16 + lr;
      ushort hh, ll; split1(o[dt][r]*inv[r], hh, ll);
      oh[(size_t)token*768 + col] = hh;
      ol[(size_t)token*768 + col] = ll;
    }
  }
}

// ---------------- router (reads split pair, reconstructs fp32)
__global__ __launch_bounds__(256) void k_router(const ushort* __restrict__ hh_h,
    const ushort* __restrict__ hh_l,
    const float* __restrict__ rw, int* __restrict__ counts,
    int* __restrict__ list, float* __restrict__ gate_slot){
  int wid = threadIdx.x >> 6, lane = threadIdx.x & 63;
  int t = blockIdx.x*4 + wid;
  float acc[8] = {0,0,0,0,0,0,0,0};
  for (int k = lane; k < 768; k += 64){
    float a = bf2f(hh_h[(size_t)t*768 + k]) + bf2f(hh_l[(size_t)t*768 + k]);
    #pragma unroll
    for (int e = 0; e < 8; e++) acc[e] += a * rw[k*8 + e];
  }
  #pragma unroll
  for (int e = 0; e < 8; e++){
    #pragma unroll
    for (int off = 32; off; off >>= 1) acc[e] += __shfl_xor(acc[e], off);
  }
  if (lane == 0){
    float v1 = -1e30f, v2 = -1e30f; int e1 = 0, e2 = 0;
    #pragma unroll
    for (int e = 0; e < 8; e++){
      float v = acc[e];
      if (v > v1){ v2 = v1; e2 = e1; v1 = v; e1 = e; }
      else if (v > v2){ v2 = v; e2 = e; }
    }
    float g1 = 1.0f/(1.0f+expf(v2-v1));
    float g2 = 1.0f - g1;
    int p1 = atomicAdd(&counts[e1], 1); list[e1*2048 + p1] = t*2;
    int p2 = atomicAdd(&counts[e2], 1); list[e2*2048 + p2] = t*2+1;
    gate_slot[t*2] = g1; gate_slot[t*2+1] = g2;
  }
}

// =================== split-bf16 MFMA GEMM, pre-split A (global) + pre-split transposed B (LDS)
// tile 64M x 128N, 4 waves (2x2 of 32x64), BK=32. B^T layout: [N][K] hi/lo planes.
// EPI: 0 ->f32, 1 +bias->f32, 2 +bias,gelu->split bf16, 3 C += gate*acc,
//      4 qkv head-major SPLIT pairs (Ch=q pair, Cl=k pair, Cv=v pair; lo at +QOFF)
#define LDKB 40
template<int EPI>
__global__ __launch_bounds__(256) void gemm_ps(
    const ushort* __restrict__ Ah, const ushort* __restrict__ Al,
    const ushort* __restrict__ Bth, const ushort* __restrict__ Btl,
    float* __restrict__ C, ushort* __restrict__ Ch, ushort* __restrict__ Cl,
    ushort* __restrict__ Cv,
    int N, int K,
    const float* __restrict__ bias, const float* __restrict__ gate, int gstride){
  __shared__ ushort BsH[128*LDKB], BsL[128*LDKB];
  int tid = threadIdx.x;
  int m0 = blockIdx.y*64, n0 = blockIdx.x*128;
  int lane = tid & 63, wid = tid >> 6;
  int wr = wid >> 1, wc = wid & 1;
  int lr = lane & 15, lg = lane >> 4;
  int brow = tid & 127, bh2 = tid >> 7;
  const ushort* bth = Bth + (size_t)(n0 + brow)*K + bh2*16;
  const ushort* btl = Btl + (size_t)(n0 + brow)*K + bh2*16;
  size_t ar0 = (size_t)(m0 + wr*32 + lr)*K + lg*8;
  size_t ar1 = (size_t)(m0 + wr*32 + 16 + lr)*K + lg*8;
  f32x4 acc[2][4] = {};
  for (int k0 = 0; k0 < K; k0 += 32){
    bf16x8 a0h = *(const bf16x8*)(Ah + ar0 + k0);
    bf16x8 a0l = *(const bf16x8*)(Al + ar0 + k0);
    bf16x8 a1h = *(const bf16x8*)(Ah + ar1 + k0);
    bf16x8 a1l = *(const bf16x8*)(Al + ar1 + k0);
    *(uint4*)&BsH[brow*LDKB + bh2*16]     = *(const uint4*)(bth + k0);
    *(uint4*)&BsH[brow*LDKB + bh2*16 + 8] = *(const uint4*)(bth + k0 + 8);
    *(uint4*)&BsL[brow*LDKB + bh2*16]     = *(const uint4*)(btl + k0);
    *(uint4*)&BsL[brow*LDKB + bh2*16 + 8] = *(const uint4*)(btl + k0 + 8);
    __syncthreads();
    #pragma unroll
    for (int nf = 0; nf < 4; nf++){
      bf16x8 bH = *(const bf16x8*)&BsH[(wc*64 + nf*16 + lr)*LDKB + lg*8];
      bf16x8 bL = *(const bf16x8*)&BsL[(wc*64 + nf*16 + lr)*LDKB + lg*8];
      acc[0][nf] = __builtin_amdgcn_mfma_f32_16x16x32_bf16(a0h, bH, acc[0][nf], 0, 0, 0);
      acc[0][nf] = __builtin_amdgcn_mfma_f32_16x16x32_bf16(a0h, bL, acc[0][nf], 0, 0, 0);
      acc[0][nf] = __builtin_amdgcn_mfma_f32_16x16x32_bf16(a0l, bH, acc[0][nf], 0, 0, 0);
      acc[1][nf] = __builtin_amdgcn_mfma_f32_16x16x32_bf16(a1h, bH, acc[1][nf], 0, 0, 0);
      acc[1][nf] = __builtin_amdgcn_mfma_f32_16x16x32_bf16(a1h, bL, acc[1][nf], 0, 0, 0);
      acc[1][nf] = __builtin_amdgcn_mfma_f32_16x16x32_bf16(a1l, bH, acc[1][nf], 0, 0, 0);
    }
    __syncthreads();
  }
  #pragma unroll
  for (int mf = 0; mf < 2; mf++){
    #pragma unroll
    for (int nf = 0; nf < 4; nf++){
      #pragma unroll
      for (int r = 0; r < 4; r++){
        int m = m0 + wr*32 + mf*16 + lg*4 + r;
        int n = n0 + wc*64 + nf*16 + lr;
        float v = acc[mf][nf][r];
        if (EPI == 1){ C[(size_t)m*N + n] = v + bias[n]; }
        else if (EPI == 2){
          ushort h, l; split1(geluf(v + bias[n]), h, l);
          Ch[(size_t)m*N + n] = h; Cl[(size_t)m*N + n] = l;
        }
        else if (EPI == 3){ C[(size_t)m*N + n] += gate[(size_t)(m >> 8)*gstride + n]*v; }
        else if (EPI == 4){
          int sec = n / 768;
          int hn = n - sec*768;
          int hd = hn >> 6, d = hn & 63;
          int bb = m >> 8, nn = m & 255;
          ushort* base = (sec == 0) ? Ch : (sec == 1) ? Cl : Cv;
          size_t idx = ((size_t)(bb*12 + hd))*16384 + nn*64 + d;
          ushort h, l; split1(v, h, l);
          base[idx] = h; base[idx + QOFF] = l;
        }
        else { C[(size_t)m*N + n] = v; }
      }
    }
  }
}

// =================== MoE grouped GEMM 1 (2-expert group): h_mid[slot] = silu(A@w1)*(A@w3)
__global__ __launch_bounds__(256) void moe_gemm1_ps(
    const ushort* __restrict__ Ah, const ushort* __restrict__ Al,
    const ushort* __restrict__ w1Th, const ushort* __restrict__ w1Tl,
    const ushort* __restrict__ w3Th, const ushort* __restrict__ w3Tl,
    const int* __restrict__ counts, const int* __restrict__ list,
    ushort* __restrict__ mh, ushort* __restrict__ ml, int ebase){
  int le = blockIdx.x >> 5, mt = blockIdx.x & 31;
  int e = ebase + le;
  int count = counts[e];
  if (mt*64 >= count) return;
  __shared__ ushort B1H[128*LDKB], B1L[128*LDKB];
  __shared__ ushort B3H[128*LDKB], B3L[128*LDKB];
  __shared__ int slotArr[64];
  int tid = threadIdx.x;
  int n0 = blockIdx.y*128;
  if (tid < 64){
    int ml2 = mt*64 + tid;
    slotArr[tid] = (ml2 < count) ? list[e*2048 + ml2] : -1;
  }
  __syncthreads();
  int lane = tid & 63, wid = tid >> 6;
  int wr = wid >> 1, wc = wid & 1;
  int lr = lane & 15, lg = lane >> 4;
  int brow = tid & 127, bh2 = tid >> 7;
  size_t eoff = (size_t)le*2048*768;
  const ushort* b1h = w1Th + eoff + (size_t)(n0 + brow)*768 + bh2*16;
  const ushort* b1l = w1Tl + eoff + (size_t)(n0 + brow)*768 + bh2*16;
  const ushort* b3h = w3Th + eoff + (size_t)(n0 + brow)*768 + bh2*16;
  const ushort* b3l = w3Tl + eoff + (size_t)(n0 + brow)*768 + bh2*16;
  int s0a = slotArr[wr*32 + lr];      int tok0 = (s0a < 0) ? 0 : (s0a >> 1);
  int s1a = slotArr[wr*32 + 16 + lr]; int tok1 = (s1a < 0) ? 0 : (s1a >> 1);
  size_t ar0 = (size_t)tok0*768 + lg*8;
  size_t ar1 = (size_t)tok1*768 + lg*8;
  f32x4 acc1[2][4] = {}, acc3[2][4] = {};
  for (int k0 = 0; k0 < 768; k0 += 32){
    bf16x8 a0h = *(const bf16x8*)(Ah + ar0 + k0);
    bf16x8 a0l = *(const bf16x8*)(Al + ar0 + k0);
    bf16x8 a1h = *(const bf16x8*)(Ah + ar1 + k0);
    bf16x8 a1l = *(const bf16x8*)(Al + ar1 + k0);
    *(uint4*)&B1H[brow*LDKB + bh2*16]     = *(const uint4*)(b1h + k0);
    *(uint4*)&B1H[brow*LDKB + bh2*16 + 8] = *(const uint4*)(b1h + k0 + 8);
    *(uint4*)&B1L[brow*LDKB + bh2*16]     = *(const uint4*)(b1l + k0);
    *(uint4*)&B1L[brow*LDKB + bh2*16 + 8] = *(const uint4*)(b1l + k0 + 8);
    *(uint4*)&B3H[brow*LDKB + bh2*16]     = *(const uint4*)(b3h + k0);
    *(uint4*)&B3H[brow*LDKB + bh2*16 + 8] = *(const uint4*)(b3h + k0 + 8);
    *(uint4*)&B3L[brow*LDKB + bh2*16]     = *(const uint4*)(b3l + k0);
    *(uint4*)&B3L[brow*LDKB + bh2*16 + 8] = *(const uint4*)(b3l + k0 + 8);
    __syncthreads();
    #pragma unroll
    for (int nf = 0; nf < 4; nf++){
      int boff = (wc*64 + nf*16 + lr)*LDKB + lg*8;
      bf16x8 c1h = *(const bf16x8*)&B1H[boff];
      bf16x8 c1l = *(const bf16x8*)&B1L[boff];
      bf16x8 c3h = *(const bf16x8*)&B3H[boff];
      bf16x8 c3l = *(const bf16x8*)&B3L[boff];
      acc1[0][nf] = __builtin_amdgcn_mfma_f32_16x16x32_bf16(a0h, c1h, acc1[0][nf], 0, 0, 0);
      acc1[0][nf] = __builtin_amdgcn_mfma_f32_16x16x32_bf16(a0h, c1l, acc1[0][nf], 0, 0, 0);
      acc1[0][nf] = __builtin_amdgcn_mfma_f32_16x16x32_bf16(a0l, c1h, acc1[0][nf], 0, 0, 0);
      acc1[1][nf] = __builtin_amdgcn_mfma_f32_16x16x32_bf16(a1h, c1h, acc1[1][nf], 0, 0, 0);
      acc1[1][nf] = __builtin_amdgcn_mfma_f32_16x16x32_bf16(a1h, c1l, acc1[1][nf], 0, 0, 0);
      acc1[1][nf] = __builtin_amdgcn_mfma_f32_16x16x32_bf16(a1l, c1h, acc1[1][nf], 0, 0, 0);
      acc3[0][nf] = __builtin_amdgcn_mfma_f32_16x16x32_bf16(a0h, c3h, acc3[0][nf], 0, 0, 0);
      acc3[0][nf] = __builtin_amdgcn_mfma_f32_16x16x32_bf16(a0h, c3l, acc3[0][nf], 0, 0, 0);
      acc3[0][nf] = __builtin_amdgcn_mfma_f32_16x16x32_bf16(a0l, c3h, acc3[0][nf], 0, 0, 0);
      acc3[1][nf] = __builtin_amdgcn_mfma_f32_16x16x32_bf16(a1h, c3h, acc3[1][nf], 0, 0, 0);
      acc3[1][nf] = __builtin_amdgcn_mfma_f32_16x16x32_bf16(a1h, c3l, acc3[1][nf], 0, 0, 0);
      acc3[1][nf] = __builtin_amdgcn_mfma_f32_16x16x32_bf16(a1l, c3h, acc3[1][nf], 0, 0, 0);
    }
    __syncthreads();
  }
  #pragma unroll
  for (int mf = 0; mf < 2; mf++){
    #pragma unroll
    for (int nf = 0; nf < 4; nf++){
      #pragma unroll
      for (int r = 0; r < 4; r++){
        int row = wr*32 + mf*16 + lg*4 + r;
        int sl = slotArr[row];
        if (sl < 0) continue;
        int n = n0 + wc*64 + nf*16 + lr;
        float v = siluf(acc1[mf][nf][r]) * acc3[mf][nf][r];
        ushort h, l; split1(v, h, l);
        mh[(size_t)sl*2048 + n] = h; ml[(size_t)sl*2048 + n] = l;
      }
    }
  }
}

// =================== MoE grouped GEMM 2 (2-expert group): y_slot[slot] = gate[slot]*(h_mid@w2), fp32
__global__ __launch_bounds__(256) void moe_gemm2_ps(
    const ushort* __restrict__ Ah, const ushort* __restrict__ Al,
    const ushort* __restrict__ w2Th, const ushort* __restrict__ w2Tl,
    const int* __restrict__ counts, const int* __restrict__ list,
    float* __restrict__ y_slot, const float* __restrict__ gate_slot, int ebase){
  int le = blockIdx.x >> 5, mt = blockIdx.x & 31;
  int e = ebase + le;
  int count = counts[e];
  if (mt*64 >= count) return;
  __shared__ ushort BsH[128*LDKB], BsL[128*LDKB];
  __shared__ int slotArr[64];
  int tid = threadIdx.x;
  int n0 = blockIdx.y*128;
  if (tid < 64){
    int ml2 = mt*64 + tid;
    slotArr[tid] = (ml2 < count) ? list[e*2048 + ml2] : -1;
  }
  __syncthreads();
  int lane = tid & 63, wid = tid >> 6;
  int wr = wid >> 1, wc = wid & 1;
  int lr = lane & 15, lg = lane >> 4;
  int brow = tid & 127, bh2 = tid >> 7;
  size_t eoff = (size_t)le*768*2048;
  const ushort* bth = w2Th + eoff + (size_t)(n0 + brow)*2048 + bh2*16;
  const ushort* btl = w2Tl + eoff + (size_t)(n0 + brow)*2048 + bh2*16;
  int s0a = slotArr[wr*32 + lr];      int sa0 = (s0a < 0) ? 0 : s0a;
  int s1a = slotArr[wr*32 + 16 + lr]; int sa1 = (s1a < 0) ? 0 : s1a;
  size_t ar0 = (size_t)sa0*2048 + lg*8;
  size_t ar1 = (size_t)sa1*2048 + lg*8;
  f32x4 acc[2][4] = {};
  for (int k0 = 0; k0 < 2048; k0 += 32){
    bf16x8 a0h = *(const bf16x8*)(Ah + ar0 + k0);
    bf16x8 a0l = *(const bf16x8*)(Al + ar0 + k0);
    bf16x8 a1h = *(const bf16x8*)(Ah + ar1 + k0);
    bf16x8 a1l = *(const bf16x8*)(Al + ar1 + k0);
    *(uint4*)&BsH[brow*LDKB + bh2*16]     = *(const uint4*)(bth + k0);
    *(uint4*)&BsH[brow*LDKB + bh2*16 + 8] = *(const uint4*)(bth + k0 + 8);
    *(uint4*)&BsL[brow*LDKB + bh2*16]     = *(const uint4*)(btl + k0);
    *(uint4*)&BsL[brow*LDKB + bh2*16 + 8] = *(const uint4*)(btl + k0 + 8);
    __syncthreads();
    #pragma unroll
    for (int nf = 0; nf < 4; nf++){
      bf16x8 bH = *(const bf16x8*)&BsH[(wc*64 + nf*16 + lr)*LDKB + lg*8];
      bf16x8 bL = *(const bf16x8*)&BsL[(wc*64 + nf*16 + lr)*LDKB + lg*8];
      acc[0][nf] = __builtin_amdgcn_mfma_f32_16x16x32_bf16(a0h, bH, acc[0][nf], 0, 0, 0);
      acc[0][nf] = __builtin_amdgcn_mfma_f32_16x16x32_bf16(a0h, bL, acc[0][nf], 0, 0, 0);
      acc[0][nf] = __builtin_amdgcn_mfma_f32_16x16x32_bf16(a0l, bH, acc[0][nf], 0, 0, 0);
      acc[1][nf] = __builtin_amdgcn_mfma_f32_16x16x32_bf16(a1h, bH, acc[1][nf], 0, 0, 0);
      acc[1][nf] = __builtin_amdgcn_mfma_f32_16x16x32_bf16(a1h, bL, acc[1][nf], 0, 0, 0);
      acc[1][nf] = __builtin_amdgcn_mfma_f32_16x16x32_bf16(a1l, bH, acc[1][nf], 0, 0, 0);
    }
    __syncthreads();
  }
  #pragma unroll
  for (int mf = 0; mf < 2; mf++){
    #pragma unroll
    for (int nf = 0; nf < 4; nf++){
      #pragma unroll
      for (int r = 0; r < 4; r++){
        int row = wr*32 + mf*16 + lg*4 + r;
        int sl = slotArr[row];
        if (sl < 0) continue;
        int n = n0 + wc*64 + nf*16 + lr;
        y_slot[(size_t)sl*768 + n] = gate_slot[sl]*acc[mf][nf][r];
      }
    }
  }
}

// ---------------- combine MoE: x += gp[b] * (y[2t] + y[2t+1])   (fp32)
__global__ void k_combine(float* __restrict__ x, const float* __restrict__ y_slot,
                          const float* __restrict__ gp){
  int idx = blockIdx.x*256 + threadIdx.x;
  int t = idx / 768, d = idx % 768;
  int b = t >> 8;
  x[idx] += gp[(size_t)b*4608 + d]*(y_slot[(size_t)(t*2)*768 + d] + y_slot[(size_t)(t*2+1)*768 + d]);
}

extern "C" void kernel_launch(void* const* d_in, const int* in_sizes, int n_in,
                              void* d_out, int out_size, void* d_ws, size_t ws_size,
                              hipStream_t stream){
  const float* x       = (const float*)d_in[0];
  const float* t       = (const float*)d_in[1];
  const int*   task_id = (const int*)d_in[2];
  const int*   mod_id  = (const int*)d_in[3];
  const float* pe1_w   = (const float*)d_in[4];
  const float* pe1_b   = (const float*)d_in[5];
  const float* pe2_w   = (const float*)d_in[6];
  const float* pe2_b   = (const float*)d_in[7];
  const float* t1_w    = (const float*)d_in[8];
  const float* t1_b    = (const float*)d_in[9];
  const float* t2_w    = (const float*)d_in[10];
  const float* t2_b    = (const float*)d_in[11];
  const float* task_tab= (const float*)d_in[12];
  const float* mod_tab = (const float*)d_in[13];
  const float* qkv_w   = (const float*)d_in[14];
  const float* proj_w  = (const float*)d_in[15];
  const float* qn_w    = (const float*)d_in[16];
  const float* kn_w    = (const float*)d_in[17];
  const float* n1_w    = (const float*)d_in[18];
  const float* n2_w    = (const float*)d_in[19];
  const float* ada_w   = (const float*)d_in[20];
  const float* ada_b   = (const float*)d_in[21];
  const float* rt_w    = (const float*)d_in[22];
  const float* w1      = (const float*)d_in[23];
  const float* w2      = (const float*)d_in[24];
  const float* w3      = (const float*)d_in[25];
  const float* fn_w    = (const float*)d_in[26];
  const float* fada_w  = (const float*)d_in[27];
  const float* fada_b  = (const float*)d_in[28];
  const float* fp_w    = (const float*)d_in[29];
  const float* fp_b    = (const float*)d_in[30];

  // ---- workspace layout (~81 MB) ----
  float* ws = (float*)d_ws;
  float* xbuf    = ws;  ws += (size_t)2048*768;
  float* cbuf    = ws;  ws += 8*768;
  float* mod     = ws;  ws += 8*4608;
  float* fmod    = ws;  ws += 8*1536;
  float* gate_slot = ws; ws += 4096;
  int* counts = (int*)ws; ws += 8;
  int* list   = (int*)ws; ws += 8*2048;
  ws += 8;
  ushort* us = (ushort*)ws;
  ushort* hh_h   = us; us += (size_t)2048*768;
  ushort* hh_l   = us; us += (size_t)2048*768;
  ushort* hm_h   = us; us += (size_t)4096*2048;
  ushort* hm_l   = us; us += (size_t)4096*2048;
  ushort* attn_h = us; us += (size_t)2048*768;
  ushort* attn_l = us; us += (size_t)2048*768;
  ushort* vt     = us; us += (size_t)96*16384;
  ushort* arena  = us; us += (size_t)8*2048*768;   // 24 MiB

  const size_t PLANE = (size_t)2048*768;
  // arena views
  ushort* aw1h = arena;
  ushort* aw1l = arena + 2*PLANE;
  ushort* aw3h = arena + 4*PLANE;
  ushort* aw3l = arena + 6*PLANE;
  ushort* aw2h = arena;
  ushort* aw2l = arena + 2*PLANE;
  ushort* aqh  = arena;
  ushort* aql  = arena + (size_t)2304*768;
  ushort* aph  = arena;
  ushort* apl  = arena + (size_t)768*768;
  float*  y_slot = (float*)(arena + 4*PLANE);      // fp32 y aliases arena planes 4-7 (dead during gemm2)
  // q/k/v split pairs alias hm (dead during attention phase); each pair = hi plane + lo plane at +QOFF
  ushort* q_pair = hm_h;                            // 2*1,572,864 u
  ushort* k_pair = hm_h + 2*QOFF;
  ushort* v_pair = hm_l;
  // pre-loop scratch aliased onto hm
  ushort* xp_h  = hm_h;
  ushort* xp_l  = hm_h + (size_t)2048*768;
  ushort* pem_h = hm_l;
  ushort* pem_l = hm_l + (size_t)2048*128;

  // patch embed
  k_patchify<<<6144, 256, 0, stream>>>(x, xp_h, xp_l);
  k_wsplit<<<dim3(2, 12, 1), 256, 0, stream>>>(pe1_w, aqh, aql, 768, 128);
  gemm_ps<2><<<dim3(1, 32), 256, 0, stream>>>(xp_h, xp_l, aqh, aql, nullptr, pem_h, pem_l, nullptr, 128, 768, pe1_b, nullptr, 0);
  k_wsplit<<<dim3(12, 2, 1), 256, 0, stream>>>(pe2_w, aqh, aql, 128, 768);
  gemm_ps<1><<<dim3(6, 32), 256, 0, stream>>>(pem_h, pem_l, aqh, aql, xbuf, nullptr, nullptr, nullptr, 768, 128, pe2_b, nullptr, 0);
  // conditioning
  k_cond<<<8, 256, 0, stream>>>(t, task_id, mod_id, t1_w, t1_b, t2_w, t2_b, task_tab, mod_tab, cbuf);

  for (int l = 0; l < 4; l++){
    k_mod<<<dim3(18, 8), 256, 0, stream>>>(cbuf, ada_w + (size_t)l*768*4608, ada_b + (size_t)l*4608, mod, 4608);
    // attention branch
    k_rms_mod<<<2048, 256, 0, stream>>>(xbuf, hh_h, hh_l, n1_w + l*768, mod + 0, mod + 768, 4608);
    k_wsplit<<<dim3(36, 12, 1), 256, 0, stream>>>(qkv_w + (size_t)l*768*2304, aqh, aql, 768, 2304);
    gemm_ps<4><<<dim3(18, 32), 256, 0, stream>>>(hh_h, hh_l, aqh, aql, nullptr, q_pair, k_pair, v_pair, 2304, 768, nullptr, nullptr, 0);
    k_qkv_prep<<<2048, 256, 0, stream>>>(q_pair, k_pair, qn_w + l*64, kn_w + l*64);
    k_vtrans<<<96, 256, 0, stream>>>(v_pair, vt);
    k_fattn<<<dim3(4, 96), 256, 0, stream>>>(q_pair, k_pair, vt, attn_h, attn_l);
    k_wsplit<<<dim3(12, 12, 1), 256, 0, stream>>>(proj_w + (size_t)l*768*768, aph, apl, 768, 768);
    gemm_ps<3><<<dim3(6, 32), 256, 0, stream>>>(attn_h, attn_l, aph, apl, xbuf, nullptr, nullptr, nullptr, 768, 768, nullptr, mod + 2*768, 4608);
    // MoE branch
    k_rms_mod<<<2048, 256, 0, stream>>>(xbuf, hh_h, hh_l, n2_w + l*768, mod + 3*768, mod + 4*768, 4608);
    hipMemsetAsync(counts, 0, 8*sizeof(int), stream);
    k_router<<<512, 256, 0, stream>>>(hh_h, hh_l, rt_w + (size_t)l*768*8, counts, list, gate_slot);
    for (int g = 0; g < 4; g++){
      int ebase = g*2;
      k_wsplit<<<dim3(32, 12, 2), 256, 0, stream>>>(w1 + ((size_t)(l*8 + ebase))*768*2048, aw1h, aw1l, 768, 2048);
      k_wsplit<<<dim3(32, 12, 2), 256, 0, stream>>>(w3 + ((size_t)(l*8 + ebase))*768*2048, aw3h, aw3l, 768, 2048);
      moe_gemm1_ps<<<dim3(64, 16), 256, 0, stream>>>(hh_h, hh_l, aw1h, aw1l, aw3h, aw3l, counts, list, hm_h, hm_l, ebase);
    }
    for (int g = 0; g < 4; g++){
      int ebase = g*2;
      k_wsplit<<<dim3(12, 32, 2), 256, 0, stream>>>(w2 + ((size_t)(l*8 + ebase))*2048*768, aw2h, aw2l, 2048, 768);
      moe_gemm2_ps<<<dim3(64, 6), 256, 0, stream>>>(hm_h, hm_l, aw2h, aw2l, counts, list, y_slot, gate_slot, ebase);
    }
    k_combine<<<6144, 256, 0, stream>>>(xbuf, y_slot, mod + 5*768);
  }

  // final layer
  k_mod<<<dim3(6, 8), 256, 0, stream>>>(cbuf, fada_w, fada_b, fmod, 1536);
  k_rms_mod<<<2048, 256, 0, stream>>>(xbuf, hh_h, hh_l, fn_w, fmod + 0, fmod + 768, 1536);
  k_wsplit<<<dim3(12, 12, 1), 256, 0, stream>>>(fp_w, aph, apl, 768, 768);
  gemm_ps<1><<<dim3(6, 32), 256, 0, stream>>>(hh_h, hh_l, aph, apl, (float*)d_out, nullptr, nullptr, nullptr, 768, 768, fp_b, nullptr, 0);
}

// Round 12
// 6017.314 us; speedup vs baseline: 1.1318x; 1.1318x over previous
//
#include <hip/hip_runtime.h>
#include <hip/hip_bf16.h>
#include <math.h>

typedef _Float16 half8 __attribute__((ext_vector_type(8)));
typedef float f32x4 __attribute__((ext_vector_type(4)));
typedef unsigned short ushort;

#define QOFFU ((size_t)1572864)   // hi->lo plane offset for qkv pairs (96*16384)

__device__ __forceinline__ float siluf(float x){ return x / (1.0f + expf(-x)); }
__device__ __forceinline__ float geluf(float x){ return 0.5f*x*(1.0f+erff(x*0.70710678118654752f)); }
__device__ __forceinline__ ushort f2h(float f){
  union { _Float16 h; ushort u; } v; v.h = (_Float16)f; return v.u;
}
__device__ __forceinline__ float h2f(ushort u){
  union { ushort u; _Float16 h; } v; v.u = u; return (float)v.h;
}
// fp16 exact split: f ~= hi + lo (error ~2^-22 rel)
__device__ __forceinline__ void split1h(float f, ushort& hi, ushort& lo){
  _Float16 h = (_Float16)f;
  _Float16 l = (_Float16)(f - (float)h);
  union { _Float16 h; ushort u; } a, b; a.h = h; b.h = l;
  hi = a.u; lo = b.u;
}

// ---------------- weight transpose+split: src fp32 [K][N] -> hi/lo fp16 [N][K], z = plane
__global__ __launch_bounds__(256) void k_wsplit2h(const float* __restrict__ src,
    ushort* __restrict__ dstH, ushort* __restrict__ dstL, int K, int N){
  __shared__ float lds[64][65];
  int n0 = blockIdx.x*64, k0 = blockIdx.y*64;
  size_t zb = (size_t)blockIdx.z*K*N;
  int tid = threadIdx.x;
  int c = tid & 63, rq = tid >> 6;
  #pragma unroll
  for (int i = 0; i < 16; i++){
    int kk = i*4 + rq;
    lds[kk][c] = src[zb + (size_t)(k0+kk)*N + n0 + c];
  }
  __syncthreads();
  #pragma unroll
  for (int i = 0; i < 16; i++){
    int nn = i*4 + rq;
    ushort h, l; split1h(lds[c][nn], h, l);
    dstH[zb + (size_t)(n0+nn)*K + k0 + c] = h;
    dstL[zb + (size_t)(n0+nn)*K + k0 + c] = l;
  }
}

// ---------------- patchify -> fp16 pair (T,768), feature order (c,ph,pw)
__global__ void k_patchify(const float* __restrict__ x,
                           ushort* __restrict__ xh, ushort* __restrict__ xl){
  int idx = blockIdx.x*256 + threadIdx.x;
  int t = idx / 768, f = idx % 768;
  int b = t >> 8, n = t & 255;
  int gh = n >> 4, gw = n & 15;
  int c = f >> 8, r = f & 255;
  int ph = r >> 4, pw = r & 15;
  float v = x[(((size_t)(b*3 + c)*256) + gh*16 + ph)*256 + gw*16 + pw];
  ushort h, l; split1h(v, h, l);
  xh[idx] = h; xl[idx] = l;
}

// ---------------- timestep + task/modality conditioning -> c (8,768)
__global__ __launch_bounds__(256) void k_cond(const float* __restrict__ t,
    const int* __restrict__ task_id, const int* __restrict__ mod_id,
    const float* __restrict__ t1w, const float* __restrict__ t1b,
    const float* __restrict__ t2w, const float* __restrict__ t2b,
    const float* __restrict__ task_tab, const float* __restrict__ mod_tab,
    float* __restrict__ c){
  __shared__ float te[256];
  __shared__ float tm[768];
  int b = blockIdx.x, tid = threadIdx.x;
  float tv = t[b];
  int i = tid & 127;
  float freq = expf(-9.210340371976184f * (float)i / 128.0f);
  float arg = tv * freq;
  te[tid] = (tid < 128) ? cosf(arg) : sinf(arg);
  __syncthreads();
  for (int d = tid; d < 768; d += 256){
    float acc = t1b[d];
    for (int k = 0; k < 256; k++) acc += te[k]*t1w[k*768+d];
    tm[d] = siluf(acc);
  }
  __syncthreads();
  for (int d = tid; d < 768; d += 256){
    float acc = t2b[d];
    for (int k = 0; k < 768; k++) acc += tm[k]*t2w[k*768+d];
    c[b*768+d] = acc + task_tab[task_id[b]*768+d] + mod_tab[mod_id[b]*768+d];
  }
}

// ---------------- out[b][n] = bias[n] + sum_k silu(c[b][k]) * W[k][n]
__global__ __launch_bounds__(256) void k_mod(const float* __restrict__ c,
    const float* __restrict__ W, const float* __restrict__ bias,
    float* __restrict__ out, int N){
  __shared__ float sc[768];
  int b = blockIdx.y, tid = threadIdx.x;
  for (int k = tid; k < 768; k += 256) sc[k] = siluf(c[b*768+k]);
  __syncthreads();
  int n = blockIdx.x*256 + tid;
  float acc = bias[n];
  for (int k = 0; k < 768; k++) acc += sc[k]*W[(size_t)k*N + n];
  out[(size_t)b*N + n] = acc;
}

// ---------------- rmsnorm + modulate -> fp16 pair
__global__ __launch_bounds__(256) void k_rms_mod(const float* __restrict__ x,
    ushort* __restrict__ oh, ushort* __restrict__ ol,
    const float* __restrict__ w,
    const float* __restrict__ shift, const float* __restrict__ scale, int mstride){
  __shared__ float red[256];
  int t = blockIdx.x, tid = threadIdx.x;
  float v0 = x[t*768 + tid], v1 = x[t*768 + 256 + tid], v2 = x[t*768 + 512 + tid];
  red[tid] = v0*v0 + v1*v1 + v2*v2;
  __syncthreads();
  for (int s2 = 128; s2 > 0; s2 >>= 1){ if (tid < s2) red[tid] += red[tid+s2]; __syncthreads(); }
  float r = rsqrtf(red[0]/768.0f + 1e-6f);
  int b = t >> 8;
  const float* sh = shift + (size_t)b*mstride;
  const float* scp = scale + (size_t)b*mstride;
  float o0 = v0*r*w[tid]    *(1.0f+scp[tid])     + sh[tid];
  float o1 = v1*r*w[tid+256]*(1.0f+scp[tid+256]) + sh[tid+256];
  float o2 = v2*r*w[tid+512]*(1.0f+scp[tid+512]) + sh[tid+512];
  ushort h, l;
  split1h(o0, h, l); oh[t*768 + tid]       = h; ol[t*768 + tid]       = l;
  split1h(o1, h, l); oh[t*768 + 256 + tid] = h; ol[t*768 + 256 + tid] = l;
  split1h(o2, h, l); oh[t*768 + 512 + tid] = h; ol[t*768 + 512 + tid] = l;
}

// ---------------- q/k head-rms + 2D RoPE on pairs; fp32 math; final fp16 into hi plane
__global__ __launch_bounds__(256) void k_qkv_prep(ushort* __restrict__ qp, ushort* __restrict__ kp,
    const float* __restrict__ qnw, const float* __restrict__ knw){
  int t = blockIdx.x;
  int wid = threadIdx.x >> 6, lane = threadIdx.x & 63;
  int n = t & 255, b = t >> 8;
  float phc = (float)(n >> 4), pwc = (float)(n & 15);
  int j = (lane & 31) >> 1;
  float freq = expf(-9.210340371976184f * (float)j / 16.0f);
  float ang = ((lane < 32) ? phc : pwc) * freq;
  float ca = cosf(ang), sa = sinf(ang);
  for (int r = wid; r < 24; r += 4){
    int isK = (r >= 12);
    int h = isK ? r - 12 : r;
    ushort* p = (isK ? kp : qp) + ((size_t)(b*12 + h))*16384 + n*64 + lane;
    float v = h2f(p[0]) + h2f(p[QOFFU]);
    float ss = v*v;
    #pragma unroll
    for (int off = 32; off; off >>= 1) ss += __shfl_xor(ss, off);
    float rr = rsqrtf(ss/64.0f + 1e-6f);
    float w = isK ? knw[lane] : qnw[lane];
    float xn = v*rr*w;
    float partner = __shfl_xor(xn, 1);
    float xr = (lane & 1) ? partner : -partner;
    float res = xn*ca + xr*sa;
    if (!isK) res *= 0.125f;
    *p = f2h(res);
  }
}

// ---------------- V transpose: v pair [bh][n][d] (hi+lo) -> vt fp16 [bh][d][n]
__global__ __launch_bounds__(256) void k_vtrans(const ushort* __restrict__ vp,
                                                ushort* __restrict__ vt){
  __shared__ float lds[64][65];
  int bh = blockIdx.x;
  int tid = threadIdx.x;
  for (int p = 0; p < 4; p++){
    int n0 = p*64;
    __syncthreads();
    #pragma unroll
    for (int i = 0; i < 16; i++){
      int tt = i*4 + (tid>>6);
      int d = tid&63;
      size_t idx = (size_t)bh*16384 + (n0 + tt)*64 + d;
      lds[tt][d] = h2f(vp[idx]) + h2f(vp[idx + QOFFU]);
    }
    __syncthreads();
    #pragma unroll
    for (int i = 0; i < 16; i++){
      int d = i*4 + (tid>>6);
      int nn = tid&63;
      vt[(size_t)bh*16384 + d*256 + n0 + nn] = f2h(lds[nn][d]);
    }
  }
}

// ---------------- fused MFMA attention, fp16, split-pair output
#define KP 72
#define VP 264
__global__ __launch_bounds__(256) void k_fattn(
    const ushort* __restrict__ qb, const ushort* __restrict__ kb,
    const ushort* __restrict__ vt,
    ushort* __restrict__ oh, ushort* __restrict__ ol){
  __shared__ ushort ksh[256*KP];
  __shared__ ushort vsh[64*VP];
  __shared__ ushort psh[4][16*VP];
  int qt = blockIdx.x, bh = blockIdx.y;
  int b = bh/12, h = bh%12;
  int tid = threadIdx.x;
  #pragma unroll
  for (int it = 0; it < 8; it++){
    int idx = it*256 + tid;
    int row = idx >> 3, ch = idx & 7;
    *(uint4*)&ksh[row*KP + ch*8] = *(const uint4*)&kb[(size_t)bh*16384 + row*64 + ch*8];
  }
  #pragma unroll
  for (int it = 0; it < 8; it++){
    int idx = it*256 + tid;
    int row = idx >> 5, ch = idx & 31;
    *(uint4*)&vsh[row*VP + ch*8] = *(const uint4*)&vt[(size_t)bh*16384 + row*256 + ch*8];
  }
  __syncthreads();
  int lane = tid & 63, w = tid >> 6;
  int lr = lane & 15, lg = lane >> 4;
  int q0 = qt*64 + w*16;
  half8 af0 = *(const half8*)&qb[(size_t)bh*16384 + (q0 + lr)*64 + lg*8];
  half8 af1 = *(const half8*)&qb[(size_t)bh*16384 + (q0 + lr)*64 + lg*8 + 32];
  f32x4 s[16];
  #pragma unroll
  for (int nt = 0; nt < 16; nt++){
    f32x4 z = {};
    z = __builtin_amdgcn_mfma_f32_16x16x32_f16(af0, *(const half8*)&ksh[(nt*16 + lr)*KP + lg*8], z, 0, 0, 0);
    z = __builtin_amdgcn_mfma_f32_16x16x32_f16(af1, *(const half8*)&ksh[(nt*16 + lr)*KP + lg*8 + 32], z, 0, 0, 0);
    s[nt] = z;
  }
  float inv[4];
  #pragma unroll
  for (int r = 0; r < 4; r++){
    float m = -1e30f;
    #pragma unroll
    for (int nt = 0; nt < 16; nt++) m = fmaxf(m, s[nt][r]);
    #pragma unroll
    for (int off = 1; off < 16; off <<= 1) m = fmaxf(m, __shfl_xor(m, off));
    float sum = 0.f;
    #pragma unroll
    for (int nt = 0; nt < 16; nt++){ float p = expf(s[nt][r] - m); s[nt][r] = p; sum += p; }
    #pragma unroll
    for (int off = 1; off < 16; off <<= 1) sum += __shfl_xor(sum, off);
    inv[r] = 1.0f/sum;
  }
  #pragma unroll
  for (int nt = 0; nt < 16; nt++){
    #pragma unroll
    for (int r = 0; r < 4; r++)
      psh[w][(lg*4 + r)*VP + nt*16 + lr] = f2h(s[nt][r]);
  }
  __syncthreads();
  f32x4 o[4] = {};
  #pragma unroll
  for (int dt = 0; dt < 4; dt++){
    #pragma unroll
    for (int k0 = 0; k0 < 8; k0++){
      half8 pa = *(const half8*)&psh[w][lr*VP + lg*8 + k0*32];
      half8 bv = *(const half8*)&vsh[(dt*16 + lr)*VP + lg*8 + k0*32];
      o[dt] = __builtin_amdgcn_mfma_f32_16x16x32_f16(pa, bv, o[dt], 0, 0, 0);
    }
  }
  #pragma unroll
  for (int dt = 0; dt < 4; dt++){
    #pragma unroll
    for (int r = 0; r < 4; r++){
      int token = b*256 + q0 + lg*4 + r;
      int col = h*64 + dt*16 + lr;
      ushort hh, ll; split1h(o[dt][r]*inv[r], hh, ll);
      oh[(size_t)token*768 + col] = hh;
      ol[(size_t)token*768 + col] = ll;
    }
  }
}

// ---------------- router (reads fp16 pair -> ~fp32 exact)
__global__ __launch_bounds__(256) void k_router(const ushort* __restrict__ hh_h,
    const ushort* __restrict__ hh_l,
    const float* __restrict__ rw, int* __restrict__ counts,
    int* __restrict__ list, float* __restrict__ gate_slot){
  int wid = threadIdx.x >> 6, lane = threadIdx.x & 63;
  int t = blockIdx.x*4 + wid;
  float acc[8] = {0,0,0,0,0,0,0,0};
  for (int k = lane; k < 768; k += 64){
    float a = h2f(hh_h[(size_t)t*768 + k]) + h2f(hh_l[(size_t)t*768 + k]);
    #pragma unroll
    for (int e = 0; e < 8; e++) acc[e] += a * rw[k*8 + e];
  }
  #pragma unroll
  for (int e = 0; e < 8; e++){
    #pragma unroll
    for (int off = 32; off; off >>= 1) acc[e] += __shfl_xor(acc[e], off);
  }
  if (lane == 0){
    float v1 = -1e30f, v2 = -1e30f; int e1 = 0, e2 = 0;
    #pragma unroll
    for (int e = 0; e < 8; e++){
      float v = acc[e];
      if (v > v1){ v2 = v1; e2 = e1; v1 = v; e1 = e; }
      else if (v > v2){ v2 = v; e2 = e; }
    }
    float g1 = 1.0f/(1.0f+expf(v2-v1));
    float g2 = 1.0f - g1;
    int p1 = atomicAdd(&counts[e1], 1); list[e1*2048 + p1] = t*2;
    int p2 = atomicAdd(&counts[e2], 1); list[e2*2048 + p2] = t*2+1;
    gate_slot[t*2] = g1; gate_slot[t*2+1] = g2;
  }
}

// =================== 3-pass fp16 MFMA GEMM: A pair (global), B pair [N][K] (LDS)
// tile 64M x 128N, 4 waves (2x2 of 32x64), BK=32.
// EPI: 1 +bias->f32, 2 +bias,gelu->pair(P0,P1), 3 C += gate*acc, 4 qkv pairs (P0/P1/P2 + QOFFU lo)
#define LDKB 40
template<int EPI>
__global__ __launch_bounds__(256) void gemm_h3(
    const ushort* __restrict__ Ah, const ushort* __restrict__ Al,
    const ushort* __restrict__ Bth, const ushort* __restrict__ Btl,
    float* __restrict__ C, ushort* __restrict__ P0, ushort* __restrict__ P1,
    ushort* __restrict__ P2,
    int N, int K,
    const float* __restrict__ bias, const float* __restrict__ gate, int gstride){
  __shared__ ushort BsH[128*LDKB], BsL[128*LDKB];
  int tid = threadIdx.x;
  int m0 = blockIdx.y*64, n0 = blockIdx.x*128;
  int lane = tid & 63, wid = tid >> 6;
  int wr = wid >> 1, wc = wid & 1;
  int lr = lane & 15, lg = lane >> 4;
  int brow = tid & 127, bh2 = tid >> 7;
  const ushort* bth = Bth + (size_t)(n0 + brow)*K + bh2*16;
  const ushort* btl = Btl + (size_t)(n0 + brow)*K + bh2*16;
  size_t ar0 = (size_t)(m0 + wr*32 + lr)*K + lg*8;
  size_t ar1 = (size_t)(m0 + wr*32 + 16 + lr)*K + lg*8;
  f32x4 acc[2][4] = {};
  for (int k0 = 0; k0 < K; k0 += 32){
    half8 a0h = *(const half8*)(Ah + ar0 + k0);
    half8 a0l = *(const half8*)(Al + ar0 + k0);
    half8 a1h = *(const half8*)(Ah + ar1 + k0);
    half8 a1l = *(const half8*)(Al + ar1 + k0);
    *(uint4*)&BsH[brow*LDKB + bh2*16]     = *(const uint4*)(bth + k0);
    *(uint4*)&BsH[brow*LDKB + bh2*16 + 8] = *(const uint4*)(bth + k0 + 8);
    *(uint4*)&BsL[brow*LDKB + bh2*16]     = *(const uint4*)(btl + k0);
    *(uint4*)&BsL[brow*LDKB + bh2*16 + 8] = *(const uint4*)(btl + k0 + 8);
    __syncthreads();
    #pragma unroll
    for (int nf = 0; nf < 4; nf++){
      half8 bH = *(const half8*)&BsH[(wc*64 + nf*16 + lr)*LDKB + lg*8];
      half8 bL = *(const half8*)&BsL[(wc*64 + nf*16 + lr)*LDKB + lg*8];
      acc[0][nf] = __builtin_amdgcn_mfma_f32_16x16x32_f16(a0h, bH, acc[0][nf], 0, 0, 0);
      acc[0][nf] = __builtin_amdgcn_mfma_f32_16x16x32_f16(a0h, bL, acc[0][nf], 0, 0, 0);
      acc[0][nf] = __builtin_amdgcn_mfma_f32_16x16x32_f16(a0l, bH, acc[0][nf], 0, 0, 0);
      acc[1][nf] = __builtin_amdgcn_mfma_f32_16x16x32_f16(a1h, bH, acc[1][nf], 0, 0, 0);
      acc[1][nf] = __builtin_amdgcn_mfma_f32_16x16x32_f16(a1h, bL, acc[1][nf], 0, 0, 0);
      acc[1][nf] = __builtin_amdgcn_mfma_f32_16x16x32_f16(a1l, bH, acc[1][nf], 0, 0, 0);
    }
    __syncthreads();
  }
  #pragma unroll
  for (int mf = 0; mf < 2; mf++){
    #pragma unroll
    for (int nf = 0; nf < 4; nf++){
      #pragma unroll
      for (int r = 0; r < 4; r++){
        int m = m0 + wr*32 + mf*16 + lg*4 + r;
        int n = n0 + wc*64 + nf*16 + lr;
        float v = acc[mf][nf][r];
        if (EPI == 1){ C[(size_t)m*N + n] = v + bias[n]; }
        else if (EPI == 2){
          ushort h, l; split1h(geluf(v + bias[n]), h, l);
          P0[(size_t)m*N + n] = h; P1[(size_t)m*N + n] = l;
        }
        else if (EPI == 3){ C[(size_t)m*N + n] += gate[(size_t)(m >> 8)*gstride + n]*v; }
        else if (EPI == 4){
          int sec = n / 768;
          int hn = n - sec*768;
          int hd = hn >> 6, d = hn & 63;
          int bb = m >> 8, nn = m & 255;
          ushort* base = (sec == 0) ? P0 : (sec == 1) ? P1 : P2;
          size_t idx = ((size_t)(bb*12 + hd))*16384 + nn*64 + d;
          ushort h, l; split1h(v, h, l);
          base[idx] = h; base[idx + QOFFU] = l;
        }
      }
    }
  }
}

// =================== MoE GEMM 1 (G-expert group), 3-pass: h_mid pair = silu(A@w1)*(A@w3)
__global__ __launch_bounds__(256) void moe_gemm1_h3(
    const ushort* __restrict__ Ah, const ushort* __restrict__ Al,
    const ushort* __restrict__ w1Th, const ushort* __restrict__ w1Tl,
    const ushort* __restrict__ w3Th, const ushort* __restrict__ w3Tl,
    const int* __restrict__ counts, const int* __restrict__ list,
    ushort* __restrict__ mh, ushort* __restrict__ ml, int ebase){
  int le = blockIdx.x >> 5, mt = blockIdx.x & 31;
  int e = ebase + le;
  int count = counts[e];
  if (mt*64 >= count) return;
  __shared__ ushort B1H[128*LDKB], B1L[128*LDKB];
  __shared__ ushort B3H[128*LDKB], B3L[128*LDKB];
  __shared__ int slotArr[64];
  int tid = threadIdx.x;
  int n0 = blockIdx.y*128;
  if (tid < 64){
    int ml2 = mt*64 + tid;
    slotArr[tid] = (ml2 < count) ? list[e*2048 + ml2] : -1;
  }
  __syncthreads();
  int lane = tid & 63, wid = tid >> 6;
  int wr = wid >> 1, wc = wid & 1;
  int lr = lane & 15, lg = lane >> 4;
  int brow = tid & 127, bh2 = tid >> 7;
  size_t eoff = (size_t)le*2048*768;
  const ushort* b1h = w1Th + eoff + (size_t)(n0 + brow)*768 + bh2*16;
  const ushort* b1l = w1Tl + eoff + (size_t)(n0 + brow)*768 + bh2*16;
  const ushort* b3h = w3Th + eoff + (size_t)(n0 + brow)*768 + bh2*16;
  const ushort* b3l = w3Tl + eoff + (size_t)(n0 + brow)*768 + bh2*16;
  int s0a = slotArr[wr*32 + lr];      int tok0 = (s0a < 0) ? 0 : (s0a >> 1);
  int s1a = slotArr[wr*32 + 16 + lr]; int tok1 = (s1a < 0) ? 0 : (s1a >> 1);
  size_t ar0 = (size_t)tok0*768 + lg*8;
  size_t ar1 = (size_t)tok1*768 + lg*8;
  f32x4 acc1[2][4] = {}, acc3[2][4] = {};
  for (int k0 = 0; k0 < 768; k0 += 32){
    half8 a0h = *(const half8*)(Ah + ar0 + k0);
    half8 a0l = *(const half8*)(Al + ar0 + k0);
    half8 a1h = *(const half8*)(Ah + ar1 + k0);
    half8 a1l = *(const half8*)(Al + ar1 + k0);
    *(uint4*)&B1H[brow*LDKB + bh2*16]     = *(const uint4*)(b1h + k0);
    *(uint4*)&B1H[brow*LDKB + bh2*16 + 8] = *(const uint4*)(b1h + k0 + 8);
    *(uint4*)&B1L[brow*LDKB + bh2*16]     = *(const uint4*)(b1l + k0);
    *(uint4*)&B1L[brow*LDKB + bh2*16 + 8] = *(const uint4*)(b1l + k0 + 8);
    *(uint4*)&B3H[brow*LDKB + bh2*16]     = *(const uint4*)(b3h + k0);
    *(uint4*)&B3H[brow*LDKB + bh2*16 + 8] = *(const uint4*)(b3h + k0 + 8);
    *(uint4*)&B3L[brow*LDKB + bh2*16]     = *(const uint4*)(b3l + k0);
    *(uint4*)&B3L[brow*LDKB + bh2*16 + 8] = *(const uint4*)(b3l + k0 + 8);
    __syncthreads();
    #pragma unroll
    for (int nf = 0; nf < 4; nf++){
      int boff = (wc*64 + nf*16 + lr)*LDKB + lg*8;
      half8 c1h = *(const half8*)&B1H[boff];
      half8 c1l = *(const half8*)&B1L[boff];
      half8 c3h = *(const half8*)&B3H[boff];
      half8 c3l = *(const half8*)&B3L[boff];
      acc1[0][nf] = __builtin_amdgcn_mfma_f32_16x16x32_f16(a0h, c1h, acc1[0][nf], 0, 0, 0);
      acc1[0][nf] = __builtin_amdgcn_mfma_f32_16x16x32_f16(a0h, c1l, acc1[0][nf], 0, 0, 0);
      acc1[0][nf] = __builtin_amdgcn_mfma_f32_16x16x32_f16(a0l, c1h, acc1[0][nf], 0, 0, 0);
      acc1[1][nf] = __builtin_amdgcn_mfma_f32_16x16x32_f16(a1h, c1h, acc1[1][nf], 0, 0, 0);
      acc1[1][nf] = __builtin_amdgcn_mfma_f32_16x16x32_f16(a1h, c1l, acc1[1][nf], 0, 0, 0);
      acc1[1][nf] = __builtin_amdgcn_mfma_f32_16x16x32_f16(a1l, c1h, acc1[1][nf], 0, 0, 0);
      acc3[0][nf] = __builtin_amdgcn_mfma_f32_16x16x32_f16(a0h, c3h, acc3[0][nf], 0, 0, 0);
      acc3[0][nf] = __builtin_amdgcn_mfma_f32_16x16x32_f16(a0h, c3l, acc3[0][nf], 0, 0, 0);
      acc3[0][nf] = __builtin_amdgcn_mfma_f32_16x16x32_f16(a0l, c3h, acc3[0][nf], 0, 0, 0);
      acc3[1][nf] = __builtin_amdgcn_mfma_f32_16x16x32_f16(a1h, c3h, acc3[1][nf], 0, 0, 0);
      acc3[1][nf] = __builtin_amdgcn_mfma_f32_16x16x32_f16(a1h, c3l, acc3[1][nf], 0, 0, 0);
      acc3[1][nf] = __builtin_amdgcn_mfma_f32_16x16x32_f16(a1l, c3h, acc3[1][nf], 0, 0, 0);
    }
    __syncthreads();
  }
  #pragma unroll
  for (int mf = 0; mf < 2; mf++){
    #pragma unroll
    for (int nf = 0; nf < 4; nf++){
      #pragma unroll
      for (int r = 0; r < 4; r++){
        int row = wr*32 + mf*16 + lg*4 + r;
        int sl = slotArr[row];
        if (sl < 0) continue;
        int n = n0 + wc*64 + nf*16 + lr;
        ushort h, l; split1h(siluf(acc1[mf][nf][r]) * acc3[mf][nf][r], h, l);
        mh[(size_t)sl*2048 + n] = h; ml[(size_t)sl*2048 + n] = l;
      }
    }
  }
}

// =================== MoE GEMM 2 (G-expert group), 3-pass: y (fp32) = gate*(h_mid@w2)
__global__ __launch_bounds__(256) void moe_gemm2_h3(
    const ushort* __restrict__ Ah, const ushort* __restrict__ Al,
    const ushort* __restrict__ w2Th, const ushort* __restrict__ w2Tl,
    const int* __restrict__ counts, const int* __restrict__ list,
    float* __restrict__ y_slot, const float* __restrict__ gate_slot, int ebase){
  int le = blockIdx.x >> 5, mt = blockIdx.x & 31;
  int e = ebase + le;
  int count = counts[e];
  if (mt*64 >= count) return;
  __shared__ ushort BsH[128*LDKB], BsL[128*LDKB];
  __shared__ int slotArr[64];
  int tid = threadIdx.x;
  int n0 = blockIdx.y*128;
  if (tid < 64){
    int ml2 = mt*64 + tid;
    slotArr[tid] = (ml2 < count) ? list[e*2048 + ml2] : -1;
  }
  __syncthreads();
  int lane = tid & 63, wid = tid >> 6;
  int wr = wid >> 1, wc = wid & 1;
  int lr = lane & 15, lg = lane >> 4;
  int brow = tid & 127, bh2 = tid >> 7;
  size_t eoff = (size_t)le*768*2048;
  const ushort* bth = w2Th + eoff + (size_t)(n0 + brow)*2048 + bh2*16;
  const ushort* btl = w2Tl + eoff + (size_t)(n0 + brow)*2048 + bh2*16;
  int s0a = slotArr[wr*32 + lr];      int sa0 = (s0a < 0) ? 0 : s0a;
  int s1a = slotArr[wr*32 + 16 + lr]; int sa1 = (s1a < 0) ? 0 : s1a;
  size_t ar0 = (size_t)sa0*2048 + lg*8;
  size_t ar1 = (size_t)sa1*2048 + lg*8;
  f32x4 acc[2][4] = {};
  for (int k0 = 0; k0 < 2048; k0 += 32){
    half8 a0h = *(const half8*)(Ah + ar0 + k0);
    half8 a0l = *(const half8*)(Al + ar0 + k0);
    half8 a1h = *(const half8*)(Ah + ar1 + k0);
    half8 a1l = *(const half8*)(Al + ar1 + k0);
    *(uint4*)&BsH[brow*LDKB + bh2*16]     = *(const uint4*)(bth + k0);
    *(uint4*)&BsH[brow*LDKB + bh2*16 + 8] = *(const uint4*)(bth + k0 + 8);
    *(uint4*)&BsL[brow*LDKB + bh2*16]     = *(const uint4*)(btl + k0);
    *(uint4*)&BsL[brow*LDKB + bh2*16 + 8] = *(const uint4*)(btl + k0 + 8);
    __syncthreads();
    #pragma unroll
    for (int nf = 0; nf < 4; nf++){
      half8 bH = *(const half8*)&BsH[(wc*64 + nf*16 + lr)*LDKB + lg*8];
      half8 bL = *(const half8*)&BsL[(wc*64 + nf*16 + lr)*LDKB + lg*8];
      acc[0][nf] = __builtin_amdgcn_mfma_f32_16x16x32_f16(a0h, bH, acc[0][nf], 0, 0, 0);
      acc[0][nf] = __builtin_amdgcn_mfma_f32_16x16x32_f16(a0h, bL, acc[0][nf], 0, 0, 0);
      acc[0][nf] = __builtin_amdgcn_mfma_f32_16x16x32_f16(a0l, bH, acc[0][nf], 0, 0, 0);
      acc[1][nf] = __builtin_amdgcn_mfma_f32_16x16x32_f16(a1h, bH, acc[1][nf], 0, 0, 0);
      acc[1][nf] = __builtin_amdgcn_mfma_f32_16x16x32_f16(a1h, bL, acc[1][nf], 0, 0, 0);
      acc[1][nf] = __builtin_amdgcn_mfma_f32_16x16x32_f16(a1l, bH, acc[1][nf], 0, 0, 0);
    }
    __syncthreads();
  }
  #pragma unroll
  for (int mf = 0; mf < 2; mf++){
    #pragma unroll
    for (int nf = 0; nf < 4; nf++){
      #pragma unroll
      for (int r = 0; r < 4; r++){
        int row = wr*32 + mf*16 + lg*4 + r;
        int sl = slotArr[row];
        if (sl < 0) continue;
        int n = n0 + wc*64 + nf*16 + lr;
        y_slot[(size_t)sl*768 + n] = gate_slot[sl]*acc[mf][nf][r];
      }
    }
  }
}

// ---------------- combine MoE: x += gp[b] * (y[2t] + y[2t+1])   (fp32)
__global__ void k_combine(float* __restrict__ x, const float* __restrict__ y_slot,
                          const float* __restrict__ gp){
  int idx = blockIdx.x*256 + threadIdx.x;
  int t = idx / 768, d = idx % 768;
  int b = t >> 8;
  x[idx] += gp[(size_t)b*4608 + d]*(y_slot[(size_t)(t*2)*768 + d] + y_slot[(size_t)(t*2+1)*768 + d]);
}

extern "C" void kernel_launch(void* const* d_in, const int* in_sizes, int n_in,
                              void* d_out, int out_size, void* d_ws, size_t ws_size,
                              hipStream_t stream){
  const float* x       = (const float*)d_in[0];
  const float* t       = (const float*)d_in[1];
  const int*   task_id = (const int*)d_in[2];
  const int*   mod_id  = (const int*)d_in[3];
  const float* pe1_w   = (const float*)d_in[4];
  const float* pe1_b   = (const float*)d_in[5];
  const float* pe2_w   = (const float*)d_in[6];
  const float* pe2_b   = (const float*)d_in[7];
  const float* t1_w    = (const float*)d_in[8];
  const float* t1_b    = (const float*)d_in[9];
  const float* t2_w    = (const float*)d_in[10];
  const float* t2_b    = (const float*)d_in[11];
  const float* task_tab= (const float*)d_in[12];
  const float* mod_tab = (const float*)d_in[13];
  const float* qkv_w   = (const float*)d_in[14];
  const float* proj_w  = (const float*)d_in[15];
  const float* qn_w    = (const float*)d_in[16];
  const float* kn_w    = (const float*)d_in[17];
  const float* n1_w    = (const float*)d_in[18];
  const float* n2_w    = (const float*)d_in[19];
  const float* ada_w   = (const float*)d_in[20];
  const float* ada_b   = (const float*)d_in[21];
  const float* rt_w    = (const float*)d_in[22];
  const float* w1      = (const float*)d_in[23];
  const float* w2      = (const float*)d_in[24];
  const float* w3      = (const float*)d_in[25];
  const float* fn_w    = (const float*)d_in[26];
  const float* fada_w  = (const float*)d_in[27];
  const float* fada_b  = (const float*)d_in[28];
  const float* fp_w    = (const float*)d_in[29];
  const float* fp_b    = (const float*)d_in[30];

  // ---- workspace layout ----
  float* ws = (float*)d_ws;
  float* xbuf    = ws;  ws += (size_t)2048*768;
  float* y_slot  = ws;  ws += (size_t)4096*768;
  float* cbuf    = ws;  ws += 8*768;
  float* mod     = ws;  ws += 8*4608;
  float* fmod    = ws;  ws += 8*1536;
  float* gate_slot = ws; ws += 4096;
  int* counts = (int*)ws; ws += 8;
  int* list   = (int*)ws; ws += 8*2048;
  ws += 8;
  ushort* us = (ushort*)ws;
  ushort* hh_h   = us; us += (size_t)2048*768;
  ushort* hh_l   = us; us += (size_t)2048*768;
  ushort* hm_h   = us; us += (size_t)4096*2048;
  ushort* hm_l   = us; us += (size_t)4096*2048;
  ushort* attn_h = us; us += (size_t)2048*768;
  ushort* attn_l = us; us += (size_t)2048*768;
  ushort* vt16   = us; us += (size_t)96*16384;
  ushort* warena = us;  // G*4 planes of 1,572,864 ushorts

  // runtime group size from ws_size (bytes). used = (warena - d_ws bytes) + G*4*PLANE*2
  size_t used_fixed = (size_t)((char*)warena - (char*)d_ws);
  const size_t PLANE = (size_t)1572864;
  int G = 1;
  if (ws_size >= used_fixed + 8*4*PLANE*2 + (8u<<20)) G = 8;
  else if (ws_size >= used_fixed + 4*4*PLANE*2 + (8u<<20)) G = 4;
  else if (ws_size >= used_fixed + 2*4*PLANE*2 + (8u<<20)) G = 2;

  ushort* aw1h = warena;
  ushort* aw1l = warena + (size_t)G*PLANE;
  ushort* aw3h = warena + (size_t)2*G*PLANE;
  ushort* aw3l = warena + (size_t)3*G*PLANE;
  ushort* aw2h = warena;                     // reuse for w2 groups
  ushort* aw2l = warena + (size_t)G*PLANE;
  ushort* aqh  = warena;                     // qkvT pair (2304*768 each)
  ushort* aql  = warena + (size_t)2304*768;
  ushort* aph  = warena;                     // projT / peT / fpT pair
  ushort* apl  = warena + (size_t)768*768;
  // q/k/v pairs alias hm (dead during attention): each pair = 2*PLANE
  ushort* q_pair = hm_h;
  ushort* k_pair = hm_h + 2*PLANE;
  ushort* v_pair = hm_l;
  // pre-loop scratch aliased onto hm
  ushort* xp_h  = hm_h;
  ushort* xp_l  = hm_h + PLANE;
  ushort* pem_h = hm_l;
  ushort* pem_l = hm_l + (size_t)2048*128;

  // patch embed
  k_patchify<<<6144, 256, 0, stream>>>(x, xp_h, xp_l);
  k_wsplit2h<<<dim3(2, 12, 1), 256, 0, stream>>>(pe1_w, aph, apl, 768, 128);
  gemm_h3<2><<<dim3(1, 32), 256, 0, stream>>>(xp_h, xp_l, aph, apl, nullptr, pem_h, pem_l, nullptr, 128, 768, pe1_b, nullptr, 0);
  k_wsplit2h<<<dim3(12, 2, 1), 256, 0, stream>>>(pe2_w, aph, apl, 128, 768);
  gemm_h3<1><<<dim3(6, 32), 256, 0, stream>>>(pem_h, pem_l, aph, apl, xbuf, nullptr, nullptr, nullptr, 768, 128, pe2_b, nullptr, 0);
  // conditioning
  k_cond<<<8, 256, 0, stream>>>(t, task_id, mod_id, t1_w, t1_b, t2_w, t2_b, task_tab, mod_tab, cbuf);

  for (int l = 0; l < 4; l++){
    k_mod<<<dim3(18, 8), 256, 0, stream>>>(cbuf, ada_w + (size_t)l*768*4608, ada_b + (size_t)l*4608, mod, 4608);
    // attention branch
    k_rms_mod<<<2048, 256, 0, stream>>>(xbuf, hh_h, hh_l, n1_w + l*768, mod + 0, mod + 768, 4608);
    k_wsplit2h<<<dim3(36, 12, 1), 256, 0, stream>>>(qkv_w + (size_t)l*768*2304, aqh, aql, 768, 2304);
    gemm_h3<4><<<dim3(18, 32), 256, 0, stream>>>(hh_h, hh_l, aqh, aql, nullptr, q_pair, k_pair, v_pair, 2304, 768, nullptr, nullptr, 0);
    k_qkv_prep<<<2048, 256, 0, stream>>>(q_pair, k_pair, qn_w + l*64, kn_w + l*64);
    k_vtrans<<<96, 256, 0, stream>>>(v_pair, vt16);
    k_fattn<<<dim3(4, 96), 256, 0, stream>>>(q_pair, k_pair, vt16, attn_h, attn_l);
    k_wsplit2h<<<dim3(12, 12, 1), 256, 0, stream>>>(proj_w + (size_t)l*768*768, aph, apl, 768, 768);
    gemm_h3<3><<<dim3(6, 32), 256, 0, stream>>>(attn_h, attn_l, aph, apl, xbuf, nullptr, nullptr, nullptr, 768, 768, nullptr, mod + 2*768, 4608);
    // MoE branch
    k_rms_mod<<<2048, 256, 0, stream>>>(xbuf, hh_h, hh_l, n2_w + l*768, mod + 3*768, mod + 4*768, 4608);
    hipMemsetAsync(counts, 0, 8*sizeof(int), stream);
    k_router<<<512, 256, 0, stream>>>(hh_h, hh_l, rt_w + (size_t)l*768*8, counts, list, gate_slot);
    for (int g = 0; g < 8; g += G){
      k_wsplit2h<<<dim3(32, 12, G), 256, 0, stream>>>(w1 + ((size_t)(l*8 + g))*768*2048, aw1h, aw1l, 768, 2048);
      k_wsplit2h<<<dim3(32, 12, G), 256, 0, stream>>>(w3 + ((size_t)(l*8 + g))*768*2048, aw3h, aw3l, 768, 2048);
      moe_gemm1_h3<<<dim3(G*32, 16), 256, 0, stream>>>(hh_h, hh_l, aw1h, aw1l, aw3h, aw3l, counts, list, hm_h, hm_l, g);
    }
    for (int g = 0; g < 8; g += G){
      k_wsplit2h<<<dim3(12, 32, G), 256, 0, stream>>>(w2 + ((size_t)(l*8 + g))*2048*768, aw2h, aw2l, 2048, 768);
      moe_gemm2_h3<<<dim3(G*32, 6), 256, 0, stream>>>(hm_h, hm_l, aw2h, aw2l, counts, list, y_slot, gate_slot, g);
    }
    k_combine<<<6144, 256, 0, stream>>>(xbuf, y_slot, mod + 5*768);
  }

  // final layer
  k_mod<<<dim3(6, 8), 256, 0, stream>>>(cbuf, fada_w, fada_b, fmod, 1536);
  k_rms_mod<<<2048, 256, 0, stream>>>(xbuf, hh_h, hh_l, fn_w, fmod + 0, fmod + 768, 1536);
  k_wsplit2h<<<dim3(12, 12, 1), 256, 0, stream>>>(fp_w, aph, apl, 768, 768);
  gemm_h3<1><<<dim3(6, 32), 256, 0, stream>>>(hh_h, hh_l, aph, apl, (float*)d_out, nullptr, nullptr, nullptr, 768, 768, fp_b, nullptr, 0);
}

// Round 13
// 3610.262 us; speedup vs baseline: 1.8864x; 1.6667x over previous
//
#include <hip/hip_runtime.h>
#include <hip/hip_bf16.h>
#include <math.h>

typedef _Float16 half8 __attribute__((ext_vector_type(8)));
typedef float f32x4 __attribute__((ext_vector_type(4)));
typedef unsigned short ushort;

#define QOFFU ((size_t)1572864)   // hi->lo plane offset for qkv pairs (96*16384)

__device__ __forceinline__ float siluf(float x){ return x / (1.0f + expf(-x)); }
__device__ __forceinline__ float geluf(float x){ return 0.5f*x*(1.0f+erff(x*0.70710678118654752f)); }
__device__ __forceinline__ ushort f2h(float f){
  union { _Float16 h; ushort u; } v; v.h = (_Float16)f; return v.u;
}
__device__ __forceinline__ float h2f(ushort u){
  union { ushort u; _Float16 h; } v; v.u = u; return (float)v.h;
}
// fp16 exact split: f ~= hi + lo (error ~2^-22 rel)
__device__ __forceinline__ void split1h(float f, ushort& hi, ushort& lo){
  _Float16 h = (_Float16)f;
  _Float16 l = (_Float16)(f - (float)h);
  union { _Float16 h; ushort u; } a, b; a.h = h; b.h = l;
  hi = a.u; lo = b.u;
}
// XCD-locality decode: panels pinned to bid%8, mt fastest within a panel
__device__ __forceinline__ void xcd_decode(int bid, int& p, int& mt){
  int r = bid & 7, q = bid >> 3;
  mt = q & 31;
  p = (q >> 5)*8 + r;
}

// ---------------- weight transpose+split: src fp32 [K][N] -> hi/lo fp16 [N][K], z = plane
__global__ __launch_bounds__(256) void k_wsplit2h(const float* __restrict__ src,
    ushort* __restrict__ dstH, ushort* __restrict__ dstL, int K, int N){
  __shared__ float lds[64][65];
  int n0 = blockIdx.x*64, k0 = blockIdx.y*64;
  size_t zb = (size_t)blockIdx.z*K*N;
  int tid = threadIdx.x;
  int c = tid & 63, rq = tid >> 6;
  #pragma unroll
  for (int i = 0; i < 16; i++){
    int kk = i*4 + rq;
    lds[kk][c] = src[zb + (size_t)(k0+kk)*N + n0 + c];
  }
  __syncthreads();
  #pragma unroll
  for (int i = 0; i < 16; i++){
    int nn = i*4 + rq;
    ushort h, l; split1h(lds[c][nn], h, l);
    dstH[zb + (size_t)(n0+nn)*K + k0 + c] = h;
    dstL[zb + (size_t)(n0+nn)*K + k0 + c] = l;
  }
}

// ---------------- patchify -> fp16 pair (T,768), feature order (c,ph,pw)
__global__ void k_patchify(const float* __restrict__ x,
                           ushort* __restrict__ xh, ushort* __restrict__ xl){
  int idx = blockIdx.x*256 + threadIdx.x;
  int t = idx / 768, f = idx % 768;
  int b = t >> 8, n = t & 255;
  int gh = n >> 4, gw = n & 15;
  int c = f >> 8, r = f & 255;
  int ph = r >> 4, pw = r & 15;
  float v = x[(((size_t)(b*3 + c)*256) + gh*16 + ph)*256 + gw*16 + pw];
  ushort h, l; split1h(v, h, l);
  xh[idx] = h; xl[idx] = l;
}

// ---------------- timestep + task/modality conditioning -> c (8,768)
__global__ __launch_bounds__(256) void k_cond(const float* __restrict__ t,
    const int* __restrict__ task_id, const int* __restrict__ mod_id,
    const float* __restrict__ t1w, const float* __restrict__ t1b,
    const float* __restrict__ t2w, const float* __restrict__ t2b,
    const float* __restrict__ task_tab, const float* __restrict__ mod_tab,
    float* __restrict__ c){
  __shared__ float te[256];
  __shared__ float tm[768];
  int b = blockIdx.x, tid = threadIdx.x;
  float tv = t[b];
  int i = tid & 127;
  float freq = expf(-9.210340371976184f * (float)i / 128.0f);
  float arg = tv * freq;
  te[tid] = (tid < 128) ? cosf(arg) : sinf(arg);
  __syncthreads();
  for (int d = tid; d < 768; d += 256){
    float acc = t1b[d];
    for (int k = 0; k < 256; k++) acc += te[k]*t1w[k*768+d];
    tm[d] = siluf(acc);
  }
  __syncthreads();
  for (int d = tid; d < 768; d += 256){
    float acc = t2b[d];
    for (int k = 0; k < 768; k++) acc += tm[k]*t2w[k*768+d];
    c[b*768+d] = acc + task_tab[task_id[b]*768+d] + mod_tab[mod_id[b]*768+d];
  }
}

// ---------------- out[b][n] = bias[n] + sum_k silu(c[b][k]) * W[k][n]
__global__ __launch_bounds__(256) void k_mod(const float* __restrict__ c,
    const float* __restrict__ W, const float* __restrict__ bias,
    float* __restrict__ out, int N){
  __shared__ float sc[768];
  int b = blockIdx.y, tid = threadIdx.x;
  for (int k = tid; k < 768; k += 256) sc[k] = siluf(c[b*768+k]);
  __syncthreads();
  int n = blockIdx.x*256 + tid;
  float acc = bias[n];
  for (int k = 0; k < 768; k++) acc += sc[k]*W[(size_t)k*N + n];
  out[(size_t)b*N + n] = acc;
}

// ---------------- rmsnorm + modulate -> fp16 pair
__global__ __launch_bounds__(256) void k_rms_mod(const float* __restrict__ x,
    ushort* __restrict__ oh, ushort* __restrict__ ol,
    const float* __restrict__ w,
    const float* __restrict__ shift, const float* __restrict__ scale, int mstride){
  __shared__ float red[256];
  int t = blockIdx.x, tid = threadIdx.x;
  float v0 = x[t*768 + tid], v1 = x[t*768 + 256 + tid], v2 = x[t*768 + 512 + tid];
  red[tid] = v0*v0 + v1*v1 + v2*v2;
  __syncthreads();
  for (int s2 = 128; s2 > 0; s2 >>= 1){ if (tid < s2) red[tid] += red[tid+s2]; __syncthreads(); }
  float r = rsqrtf(red[0]/768.0f + 1e-6f);
  int b = t >> 8;
  const float* sh = shift + (size_t)b*mstride;
  const float* scp = scale + (size_t)b*mstride;
  float o0 = v0*r*w[tid]    *(1.0f+scp[tid])     + sh[tid];
  float o1 = v1*r*w[tid+256]*(1.0f+scp[tid+256]) + sh[tid+256];
  float o2 = v2*r*w[tid+512]*(1.0f+scp[tid+512]) + sh[tid+512];
  ushort h, l;
  split1h(o0, h, l); oh[t*768 + tid]       = h; ol[t*768 + tid]       = l;
  split1h(o1, h, l); oh[t*768 + 256 + tid] = h; ol[t*768 + 256 + tid] = l;
  split1h(o2, h, l); oh[t*768 + 512 + tid] = h; ol[t*768 + 512 + tid] = l;
}

// ---------------- q/k head-rms + 2D RoPE on pairs; fp32 math; final fp16 into hi plane
__global__ __launch_bounds__(256) void k_qkv_prep(ushort* __restrict__ qp, ushort* __restrict__ kp,
    const float* __restrict__ qnw, const float* __restrict__ knw){
  int t = blockIdx.x;
  int wid = threadIdx.x >> 6, lane = threadIdx.x & 63;
  int n = t & 255, b = t >> 8;
  float phc = (float)(n >> 4), pwc = (float)(n & 15);
  int j = (lane & 31) >> 1;
  float freq = expf(-9.210340371976184f * (float)j / 16.0f);
  float ang = ((lane < 32) ? phc : pwc) * freq;
  float ca = cosf(ang), sa = sinf(ang);
  for (int r = wid; r < 24; r += 4){
    int isK = (r >= 12);
    int h = isK ? r - 12 : r;
    ushort* p = (isK ? kp : qp) + ((size_t)(b*12 + h))*16384 + n*64 + lane;
    float v = h2f(p[0]) + h2f(p[QOFFU]);
    float ss = v*v;
    #pragma unroll
    for (int off = 32; off; off >>= 1) ss += __shfl_xor(ss, off);
    float rr = rsqrtf(ss/64.0f + 1e-6f);
    float w = isK ? knw[lane] : qnw[lane];
    float xn = v*rr*w;
    float partner = __shfl_xor(xn, 1);
    float xr = (lane & 1) ? partner : -partner;
    float res = xn*ca + xr*sa;
    if (!isK) res *= 0.125f;
    *p = f2h(res);
  }
}

// ---------------- V transpose: v pair [bh][n][d] (hi+lo) -> vt fp16 [bh][d][n]
__global__ __launch_bounds__(256) void k_vtrans(const ushort* __restrict__ vp,
                                                ushort* __restrict__ vt){
  __shared__ float lds[64][65];
  int bh = blockIdx.x;
  int tid = threadIdx.x;
  for (int p = 0; p < 4; p++){
    int n0 = p*64;
    __syncthreads();
    #pragma unroll
    for (int i = 0; i < 16; i++){
      int tt = i*4 + (tid>>6);
      int d = tid&63;
      size_t idx = (size_t)bh*16384 + (n0 + tt)*64 + d;
      lds[tt][d] = h2f(vp[idx]) + h2f(vp[idx + QOFFU]);
    }
    __syncthreads();
    #pragma unroll
    for (int i = 0; i < 16; i++){
      int d = i*4 + (tid>>6);
      int nn = tid&63;
      vt[(size_t)bh*16384 + d*256 + n0 + nn] = f2h(lds[nn][d]);
    }
  }
}

// ---------------- fused MFMA attention, fp16, split-pair output
#define KP 72
#define VP 264
__global__ __launch_bounds__(256) void k_fattn(
    const ushort* __restrict__ qb, const ushort* __restrict__ kb,
    const ushort* __restrict__ vt,
    ushort* __restrict__ oh, ushort* __restrict__ ol){
  __shared__ ushort ksh[256*KP];
  __shared__ ushort vsh[64*VP];
  __shared__ ushort psh[4][16*VP];
  int qt = blockIdx.x, bh = blockIdx.y;
  int b = bh/12, h = bh%12;
  int tid = threadIdx.x;
  #pragma unroll
  for (int it = 0; it < 8; it++){
    int idx = it*256 + tid;
    int row = idx >> 3, ch = idx & 7;
    *(uint4*)&ksh[row*KP + ch*8] = *(const uint4*)&kb[(size_t)bh*16384 + row*64 + ch*8];
  }
  #pragma unroll
  for (int it = 0; it < 8; it++){
    int idx = it*256 + tid;
    int row = idx >> 5, ch = idx & 31;
    *(uint4*)&vsh[row*VP + ch*8] = *(const uint4*)&vt[(size_t)bh*16384 + row*256 + ch*8];
  }
  __syncthreads();
  int lane = tid & 63, w = tid >> 6;
  int lr = lane & 15, lg = lane >> 4;
  int q0 = qt*64 + w*16;
  half8 af0 = *(const half8*)&qb[(size_t)bh*16384 + (q0 + lr)*64 + lg*8];
  half8 af1 = *(const half8*)&qb[(size_t)bh*16384 + (q0 + lr)*64 + lg*8 + 32];
  f32x4 s[16];
  #pragma unroll
  for (int nt = 0; nt < 16; nt++){
    f32x4 z = {};
    z = __builtin_amdgcn_mfma_f32_16x16x32_f16(af0, *(const half8*)&ksh[(nt*16 + lr)*KP + lg*8], z, 0, 0, 0);
    z = __builtin_amdgcn_mfma_f32_16x16x32_f16(af1, *(const half8*)&ksh[(nt*16 + lr)*KP + lg*8 + 32], z, 0, 0, 0);
    s[nt] = z;
  }
  float inv[4];
  #pragma unroll
  for (int r = 0; r < 4; r++){
    float m = -1e30f;
    #pragma unroll
    for (int nt = 0; nt < 16; nt++) m = fmaxf(m, s[nt][r]);
    #pragma unroll
    for (int off = 1; off < 16; off <<= 1) m = fmaxf(m, __shfl_xor(m, off));
    float sum = 0.f;
    #pragma unroll
    for (int nt = 0; nt < 16; nt++){ float p = expf(s[nt][r] - m); s[nt][r] = p; sum += p; }
    #pragma unroll
    for (int off = 1; off < 16; off <<= 1) sum += __shfl_xor(sum, off);
    inv[r] = 1.0f/sum;
  }
  #pragma unroll
  for (int nt = 0; nt < 16; nt++){
    #pragma unroll
    for (int r = 0; r < 4; r++)
      psh[w][(lg*4 + r)*VP + nt*16 + lr] = f2h(s[nt][r]);
  }
  __syncthreads();
  f32x4 o[4] = {};
  #pragma unroll
  for (int dt = 0; dt < 4; dt++){
    #pragma unroll
    for (int k0 = 0; k0 < 8; k0++){
      half8 pa = *(const half8*)&psh[w][lr*VP + lg*8 + k0*32];
      half8 bv = *(const half8*)&vsh[(dt*16 + lr)*VP + lg*8 + k0*32];
      o[dt] = __builtin_amdgcn_mfma_f32_16x16x32_f16(pa, bv, o[dt], 0, 0, 0);
    }
  }
  #pragma unroll
  for (int dt = 0; dt < 4; dt++){
    #pragma unroll
    for (int r = 0; r < 4; r++){
      int token = b*256 + q0 + lg*4 + r;
      int col = h*64 + dt*16 + lr;
      ushort hh, ll; split1h(o[dt][r]*inv[r], hh, ll);
      oh[(size_t)token*768 + col] = hh;
      ol[(size_t)token*768 + col] = ll;
    }
  }
}

// ---------------- router (reads fp16 pair -> ~fp32 exact)
__global__ __launch_bounds__(256) void k_router(const ushort* __restrict__ hh_h,
    const ushort* __restrict__ hh_l,
    const float* __restrict__ rw, int* __restrict__ counts,
    int* __restrict__ list, float* __restrict__ gate_slot){
  int wid = threadIdx.x >> 6, lane = threadIdx.x & 63;
  int t = blockIdx.x*4 + wid;
  float acc[8] = {0,0,0,0,0,0,0,0};
  for (int k = lane; k < 768; k += 64){
    float a = h2f(hh_h[(size_t)t*768 + k]) + h2f(hh_l[(size_t)t*768 + k]);
    #pragma unroll
    for (int e = 0; e < 8; e++) acc[e] += a * rw[k*8 + e];
  }
  #pragma unroll
  for (int e = 0; e < 8; e++){
    #pragma unroll
    for (int off = 32; off; off >>= 1) acc[e] += __shfl_xor(acc[e], off);
  }
  if (lane == 0){
    float v1 = -1e30f, v2 = -1e30f; int e1 = 0, e2 = 0;
    #pragma unroll
    for (int e = 0; e < 8; e++){
      float v = acc[e];
      if (v > v1){ v2 = v1; e2 = e1; v1 = v; e1 = e; }
      else if (v > v2){ v2 = v; e2 = e; }
    }
    float g1 = 1.0f/(1.0f+expf(v2-v1));
    float g2 = 1.0f - g1;
    int p1 = atomicAdd(&counts[e1], 1); list[e1*2048 + p1] = t*2;
    int p2 = atomicAdd(&counts[e2], 1); list[e2*2048 + p2] = t*2+1;
    gate_slot[t*2] = g1; gate_slot[t*2+1] = g2;
  }
}

// =================== 3-pass fp16 MFMA GEMM: A pair (global), B pair [N][K] (LDS)
// 1D grid, XCD-swizzled: panel = n-tile (pinned to bid%8), mt fastest. M fixed 2048 (MT=32).
// EPI: 1 +bias->f32, 2 +bias,gelu->pair(P0,P1), 3 C += gate*acc, 4 qkv pairs (P0/P1/P2 + QOFFU lo)
#define LDKB 40
template<int EPI>
__global__ __launch_bounds__(256) void gemm_h3(
    const ushort* __restrict__ Ah, const ushort* __restrict__ Al,
    const ushort* __restrict__ Bth, const ushort* __restrict__ Btl,
    float* __restrict__ C, ushort* __restrict__ P0, ushort* __restrict__ P1,
    ushort* __restrict__ P2,
    int N, int K,
    const float* __restrict__ bias, const float* __restrict__ gate, int gstride){
  int pan, mt; xcd_decode(blockIdx.x, pan, mt);
  int NT = N >> 7;
  if (pan >= NT) return;
  int m0 = mt*64, n0 = pan*128;
  __shared__ ushort BsH[128*LDKB], BsL[128*LDKB];
  int tid = threadIdx.x;
  int lane = tid & 63, wid = tid >> 6;
  int wr = wid >> 1, wc = wid & 1;
  int lr = lane & 15, lg = lane >> 4;
  int brow = tid & 127, bh2 = tid >> 7;
  const ushort* bth = Bth + (size_t)(n0 + brow)*K + bh2*16;
  const ushort* btl = Btl + (size_t)(n0 + brow)*K + bh2*16;
  size_t ar0 = (size_t)(m0 + wr*32 + lr)*K + lg*8;
  size_t ar1 = (size_t)(m0 + wr*32 + 16 + lr)*K + lg*8;
  f32x4 acc[2][4] = {};
  for (int k0 = 0; k0 < K; k0 += 32){
    half8 a0h = *(const half8*)(Ah + ar0 + k0);
    half8 a0l = *(const half8*)(Al + ar0 + k0);
    half8 a1h = *(const half8*)(Ah + ar1 + k0);
    half8 a1l = *(const half8*)(Al + ar1 + k0);
    *(uint4*)&BsH[brow*LDKB + bh2*16]     = *(const uint4*)(bth + k0);
    *(uint4*)&BsH[brow*LDKB + bh2*16 + 8] = *(const uint4*)(bth + k0 + 8);
    *(uint4*)&BsL[brow*LDKB + bh2*16]     = *(const uint4*)(btl + k0);
    *(uint4*)&BsL[brow*LDKB + bh2*16 + 8] = *(const uint4*)(btl + k0 + 8);
    __syncthreads();
    #pragma unroll
    for (int nf = 0; nf < 4; nf++){
      half8 bH = *(const half8*)&BsH[(wc*64 + nf*16 + lr)*LDKB + lg*8];
      half8 bL = *(const half8*)&BsL[(wc*64 + nf*16 + lr)*LDKB + lg*8];
      acc[0][nf] = __builtin_amdgcn_mfma_f32_16x16x32_f16(a0h, bH, acc[0][nf], 0, 0, 0);
      acc[0][nf] = __builtin_amdgcn_mfma_f32_16x16x32_f16(a0h, bL, acc[0][nf], 0, 0, 0);
      acc[0][nf] = __builtin_amdgcn_mfma_f32_16x16x32_f16(a0l, bH, acc[0][nf], 0, 0, 0);
      acc[1][nf] = __builtin_amdgcn_mfma_f32_16x16x32_f16(a1h, bH, acc[1][nf], 0, 0, 0);
      acc[1][nf] = __builtin_amdgcn_mfma_f32_16x16x32_f16(a1h, bL, acc[1][nf], 0, 0, 0);
      acc[1][nf] = __builtin_amdgcn_mfma_f32_16x16x32_f16(a1l, bH, acc[1][nf], 0, 0, 0);
    }
    __syncthreads();
  }
  #pragma unroll
  for (int mf = 0; mf < 2; mf++){
    #pragma unroll
    for (int nf = 0; nf < 4; nf++){
      #pragma unroll
      for (int r = 0; r < 4; r++){
        int m = m0 + wr*32 + mf*16 + lg*4 + r;
        int n = n0 + wc*64 + nf*16 + lr;
        float v = acc[mf][nf][r];
        if (EPI == 1){ C[(size_t)m*N + n] = v + bias[n]; }
        else if (EPI == 2){
          ushort h, l; split1h(geluf(v + bias[n]), h, l);
          P0[(size_t)m*N + n] = h; P1[(size_t)m*N + n] = l;
        }
        else if (EPI == 3){ C[(size_t)m*N + n] += gate[(size_t)(m >> 8)*gstride + n]*v; }
        else if (EPI == 4){
          int sec = n / 768;
          int hn = n - sec*768;
          int hd = hn >> 6, d = hn & 63;
          int bb = m >> 8, nn = m & 255;
          ushort* base = (sec == 0) ? P0 : (sec == 1) ? P1 : P2;
          size_t idx = ((size_t)(bb*12 + hd))*16384 + nn*64 + d;
          ushort h, l; split1h(v, h, l);
          base[idx] = h; base[idx + QOFFU] = l;
        }
      }
    }
  }
}

// =================== MoE GEMM 1 (G-expert group), 3-pass, XCD-swizzled
// panel = le*16 + nt (G*16 panels), mt in [0,32)
__global__ __launch_bounds__(256) void moe_gemm1_h3(
    const ushort* __restrict__ Ah, const ushort* __restrict__ Al,
    const ushort* __restrict__ w1Th, const ushort* __restrict__ w1Tl,
    const ushort* __restrict__ w3Th, const ushort* __restrict__ w3Tl,
    const int* __restrict__ counts, const int* __restrict__ list,
    ushort* __restrict__ mh, ushort* __restrict__ ml, int ebase, int G){
  int pan, mt; xcd_decode(blockIdx.x, pan, mt);
  if (pan >= G*16) return;
  int le = pan >> 4;
  int e = ebase + le;
  int count = counts[e];
  if (mt*64 >= count) return;
  int n0 = (pan & 15)*128;
  __shared__ ushort B1H[128*LDKB], B1L[128*LDKB];
  __shared__ ushort B3H[128*LDKB], B3L[128*LDKB];
  __shared__ int slotArr[64];
  int tid = threadIdx.x;
  if (tid < 64){
    int ml2 = mt*64 + tid;
    slotArr[tid] = (ml2 < count) ? list[e*2048 + ml2] : -1;
  }
  __syncthreads();
  int lane = tid & 63, wid = tid >> 6;
  int wr = wid >> 1, wc = wid & 1;
  int lr = lane & 15, lg = lane >> 4;
  int brow = tid & 127, bh2 = tid >> 7;
  size_t eoff = (size_t)le*2048*768;
  const ushort* b1h = w1Th + eoff + (size_t)(n0 + brow)*768 + bh2*16;
  const ushort* b1l = w1Tl + eoff + (size_t)(n0 + brow)*768 + bh2*16;
  const ushort* b3h = w3Th + eoff + (size_t)(n0 + brow)*768 + bh2*16;
  const ushort* b3l = w3Tl + eoff + (size_t)(n0 + brow)*768 + bh2*16;
  int s0a = slotArr[wr*32 + lr];      int tok0 = (s0a < 0) ? 0 : (s0a >> 1);
  int s1a = slotArr[wr*32 + 16 + lr]; int tok1 = (s1a < 0) ? 0 : (s1a >> 1);
  size_t ar0 = (size_t)tok0*768 + lg*8;
  size_t ar1 = (size_t)tok1*768 + lg*8;
  f32x4 acc1[2][4] = {}, acc3[2][4] = {};
  for (int k0 = 0; k0 < 768; k0 += 32){
    half8 a0h = *(const half8*)(Ah + ar0 + k0);
    half8 a0l = *(const half8*)(Al + ar0 + k0);
    half8 a1h = *(const half8*)(Ah + ar1 + k0);
    half8 a1l = *(const half8*)(Al + ar1 + k0);
    *(uint4*)&B1H[brow*LDKB + bh2*16]     = *(const uint4*)(b1h + k0);
    *(uint4*)&B1H[brow*LDKB + bh2*16 + 8] = *(const uint4*)(b1h + k0 + 8);
    *(uint4*)&B1L[brow*LDKB + bh2*16]     = *(const uint4*)(b1l + k0);
    *(uint4*)&B1L[brow*LDKB + bh2*16 + 8] = *(const uint4*)(b1l + k0 + 8);
    *(uint4*)&B3H[brow*LDKB + bh2*16]     = *(const uint4*)(b3h + k0);
    *(uint4*)&B3H[brow*LDKB + bh2*16 + 8] = *(const uint4*)(b3h + k0 + 8);
    *(uint4*)&B3L[brow*LDKB + bh2*16]     = *(const uint4*)(b3l + k0);
    *(uint4*)&B3L[brow*LDKB + bh2*16 + 8] = *(const uint4*)(b3l + k0 + 8);
    __syncthreads();
    #pragma unroll
    for (int nf = 0; nf < 4; nf++){
      int boff = (wc*64 + nf*16 + lr)*LDKB + lg*8;
      half8 c1h = *(const half8*)&B1H[boff];
      half8 c1l = *(const half8*)&B1L[boff];
      half8 c3h = *(const half8*)&B3H[boff];
      half8 c3l = *(const half8*)&B3L[boff];
      acc1[0][nf] = __builtin_amdgcn_mfma_f32_16x16x32_f16(a0h, c1h, acc1[0][nf], 0, 0, 0);
      acc1[0][nf] = __builtin_amdgcn_mfma_f32_16x16x32_f16(a0h, c1l, acc1[0][nf], 0, 0, 0);
      acc1[0][nf] = __builtin_amdgcn_mfma_f32_16x16x32_f16(a0l, c1h, acc1[0][nf], 0, 0, 0);
      acc1[1][nf] = __builtin_amdgcn_mfma_f32_16x16x32_f16(a1h, c1h, acc1[1][nf], 0, 0, 0);
      acc1[1][nf] = __builtin_amdgcn_mfma_f32_16x16x32_f16(a1h, c1l, acc1[1][nf], 0, 0, 0);
      acc1[1][nf] = __builtin_amdgcn_mfma_f32_16x16x32_f16(a1l, c1h, acc1[1][nf], 0, 0, 0);
      acc3[0][nf] = __builtin_amdgcn_mfma_f32_16x16x32_f16(a0h, c3h, acc3[0][nf], 0, 0, 0);
      acc3[0][nf] = __builtin_amdgcn_mfma_f32_16x16x32_f16(a0h, c3l, acc3[0][nf], 0, 0, 0);
      acc3[0][nf] = __builtin_amdgcn_mfma_f32_16x16x32_f16(a0l, c3h, acc3[0][nf], 0, 0, 0);
      acc3[1][nf] = __builtin_amdgcn_mfma_f32_16x16x32_f16(a1h, c3h, acc3[1][nf], 0, 0, 0);
      acc3[1][nf] = __builtin_amdgcn_mfma_f32_16x16x32_f16(a1h, c3l, acc3[1][nf], 0, 0, 0);
      acc3[1][nf] = __builtin_amdgcn_mfma_f32_16x16x32_f16(a1l, c3h, acc3[1][nf], 0, 0, 0);
    }
    __syncthreads();
  }
  #pragma unroll
  for (int mf = 0; mf < 2; mf++){
    #pragma unroll
    for (int nf = 0; nf < 4; nf++){
      #pragma unroll
      for (int r = 0; r < 4; r++){
        int row = wr*32 + mf*16 + lg*4 + r;
        int sl = slotArr[row];
        if (sl < 0) continue;
        int n = n0 + wc*64 + nf*16 + lr;
        ushort h, l; split1h(siluf(acc1[mf][nf][r]) * acc3[mf][nf][r], h, l);
        mh[(size_t)sl*2048 + n] = h; ml[(size_t)sl*2048 + n] = l;
      }
    }
  }
}

// =================== MoE GEMM 2 (G-expert group), 3-pass, XCD-swizzled
// panel = le*6 + nt (G*6 panels), mt in [0,32)
__global__ __launch_bounds__(256) void moe_gemm2_h3(
    const ushort* __restrict__ Ah, const ushort* __restrict__ Al,
    const ushort* __restrict__ w2Th, const ushort* __restrict__ w2Tl,
    const int* __restrict__ counts, const int* __restrict__ list,
    float* __restrict__ y_slot, const float* __restrict__ gate_slot, int ebase, int G){
  int pan, mt; xcd_decode(blockIdx.x, pan, mt);
  if (pan >= G*6) return;
  int le = pan / 6;
  int e = ebase + le;
  int count = counts[e];
  if (mt*64 >= count) return;
  int n0 = (pan % 6)*128;
  __shared__ ushort BsH[128*LDKB], BsL[128*LDKB];
  __shared__ int slotArr[64];
  int tid = threadIdx.x;
  if (tid < 64){
    int ml2 = mt*64 + tid;
    slotArr[tid] = (ml2 < count) ? list[e*2048 + ml2] : -1;
  }
  __syncthreads();
  int lane = tid & 63, wid = tid >> 6;
  int wr = wid >> 1, wc = wid & 1;
  int lr = lane & 15, lg = lane >> 4;
  int brow = tid & 127, bh2 = tid >> 7;
  size_t eoff = (size_t)le*768*2048;
  const ushort* bth = w2Th + eoff + (size_t)(n0 + brow)*2048 + bh2*16;
  const ushort* btl = w2Tl + eoff + (size_t)(n0 + brow)*2048 + bh2*16;
  int s0a = slotArr[wr*32 + lr];      int sa0 = (s0a < 0) ? 0 : s0a;
  int s1a = slotArr[wr*32 + 16 + lr]; int sa1 = (s1a < 0) ? 0 : s1a;
  size_t ar0 = (size_t)sa0*2048 + lg*8;
  size_t ar1 = (size_t)sa1*2048 + lg*8;
  f32x4 acc[2][4] = {};
  for (int k0 = 0; k0 < 2048; k0 += 32){
    half8 a0h = *(const half8*)(Ah + ar0 + k0);
    half8 a0l = *(const half8*)(Al + ar0 + k0);
    half8 a1h = *(const half8*)(Ah + ar1 + k0);
    half8 a1l = *(const half8*)(Al + ar1 + k0);
    *(uint4*)&BsH[brow*LDKB + bh2*16]     = *(const uint4*)(bth + k0);
    *(uint4*)&BsH[brow*LDKB + bh2*16 + 8] = *(const uint4*)(bth + k0 + 8);
    *(uint4*)&BsL[brow*LDKB + bh2*16]     = *(const uint4*)(btl + k0);
    *(uint4*)&BsL[brow*LDKB + bh2*16 + 8] = *(const uint4*)(btl + k0 + 8);
    __syncthreads();
    #pragma unroll
    for (int nf = 0; nf < 4; nf++){
      half8 bH = *(const half8*)&BsH[(wc*64 + nf*16 + lr)*LDKB + lg*8];
      half8 bL = *(const half8*)&BsL[(wc*64 + nf*16 + lr)*LDKB + lg*8];
      acc[0][nf] = __builtin_amdgcn_mfma_f32_16x16x32_f16(a0h, bH, acc[0][nf], 0, 0, 0);
      acc[0][nf] = __builtin_amdgcn_mfma_f32_16x16x32_f16(a0h, bL, acc[0][nf], 0, 0, 0);
      acc[0][nf] = __builtin_amdgcn_mfma_f32_16x16x32_f16(a0l, bH, acc[0][nf], 0, 0, 0);
      acc[1][nf] = __builtin_amdgcn_mfma_f32_16x16x32_f16(a1h, bH, acc[1][nf], 0, 0, 0);
      acc[1][nf] = __builtin_amdgcn_mfma_f32_16x16x32_f16(a1h, bL, acc[1][nf], 0, 0, 0);
      acc[1][nf] = __builtin_amdgcn_mfma_f32_16x16x32_f16(a1l, bH, acc[1][nf], 0, 0, 0);
    }
    __syncthreads();
  }
  #pragma unroll
  for (int mf = 0; mf < 2; mf++){
    #pragma unroll
    for (int nf = 0; nf < 4; nf++){
      #pragma unroll
      for (int r = 0; r < 4; r++){
        int row = wr*32 + mf*16 + lg*4 + r;
        int sl = slotArr[row];
        if (sl < 0) continue;
        int n = n0 + wc*64 + nf*16 + lr;
        y_slot[(size_t)sl*768 + n] = gate_slot[sl]*acc[mf][nf][r];
      }
    }
  }
}

// ---------------- combine MoE: x += gp[b] * (y[2t] + y[2t+1])   (fp32)
__global__ void k_combine(float* __restrict__ x, const float* __restrict__ y_slot,
                          const float* __restrict__ gp){
  int idx = blockIdx.x*256 + threadIdx.x;
  int t = idx / 768, d = idx % 768;
  int b = t >> 8;
  x[idx] += gp[(size_t)b*4608 + d]*(y_slot[(size_t)(t*2)*768 + d] + y_slot[(size_t)(t*2+1)*768 + d]);
}

extern "C" void kernel_launch(void* const* d_in, const int* in_sizes, int n_in,
                              void* d_out, int out_size, void* d_ws, size_t ws_size,
                              hipStream_t stream){
  const float* x       = (const float*)d_in[0];
  const float* t       = (const float*)d_in[1];
  const int*   task_id = (const int*)d_in[2];
  const int*   mod_id  = (const int*)d_in[3];
  const float* pe1_w   = (const float*)d_in[4];
  const float* pe1_b   = (const float*)d_in[5];
  const float* pe2_w   = (const float*)d_in[6];
  const float* pe2_b   = (const float*)d_in[7];
  const float* t1_w    = (const float*)d_in[8];
  const float* t1_b    = (const float*)d_in[9];
  const float* t2_w    = (const float*)d_in[10];
  const float* t2_b    = (const float*)d_in[11];
  const float* task_tab= (const float*)d_in[12];
  const float* mod_tab = (const float*)d_in[13];
  const float* qkv_w   = (const float*)d_in[14];
  const float* proj_w  = (const float*)d_in[15];
  const float* qn_w    = (const float*)d_in[16];
  const float* kn_w    = (const float*)d_in[17];
  const float* n1_w    = (const float*)d_in[18];
  const float* n2_w    = (const float*)d_in[19];
  const float* ada_w   = (const float*)d_in[20];
  const float* ada_b   = (const float*)d_in[21];
  const float* rt_w    = (const float*)d_in[22];
  const float* w1      = (const float*)d_in[23];
  const float* w2      = (const float*)d_in[24];
  const float* w3      = (const float*)d_in[25];
  const float* fn_w    = (const float*)d_in[26];
  const float* fada_w  = (const float*)d_in[27];
  const float* fada_b  = (const float*)d_in[28];
  const float* fp_w    = (const float*)d_in[29];
  const float* fp_b    = (const float*)d_in[30];

  // ---- workspace layout ----
  float* ws = (float*)d_ws;
  float* xbuf    = ws;  ws += (size_t)2048*768;
  float* y_slot  = ws;  ws += (size_t)4096*768;
  float* cbuf    = ws;  ws += 8*768;
  float* mod     = ws;  ws += 8*4608;
  float* fmod    = ws;  ws += 8*1536;
  float* gate_slot = ws; ws += 4096;
  int* counts = (int*)ws; ws += 8;
  int* list   = (int*)ws; ws += 8*2048;
  ws += 8;
  ushort* us = (ushort*)ws;
  ushort* hh_h   = us; us += (size_t)2048*768;
  ushort* hh_l   = us; us += (size_t)2048*768;
  ushort* hm_h   = us; us += (size_t)4096*2048;
  ushort* hm_l   = us; us += (size_t)4096*2048;
  ushort* attn_h = us; us += (size_t)2048*768;
  ushort* attn_l = us; us += (size_t)2048*768;
  ushort* vt16   = us; us += (size_t)96*16384;
  ushort* warena = us;  // G*4 planes of 1,572,864 ushorts

  size_t used_fixed = (size_t)((char*)warena - (char*)d_ws);
  const size_t PLANE = (size_t)1572864;
  int G = 1;
  if (ws_size >= used_fixed + 8*4*PLANE*2 + (8u<<20)) G = 8;
  else if (ws_size >= used_fixed + 4*4*PLANE*2 + (8u<<20)) G = 4;
  else if (ws_size >= used_fixed + 2*4*PLANE*2 + (8u<<20)) G = 2;

  ushort* aw1h = warena;
  ushort* aw1l = warena + (size_t)G*PLANE;
  ushort* aw3h = warena + (size_t)2*G*PLANE;
  ushort* aw3l = warena + (size_t)3*G*PLANE;
  ushort* aw2h = warena;
  ushort* aw2l = warena + (size_t)G*PLANE;
  ushort* aqh  = warena;
  ushort* aql  = warena + (size_t)2304*768;
  ushort* aph  = warena;
  ushort* apl  = warena + (size_t)768*768;
  ushort* q_pair = hm_h;
  ushort* k_pair = hm_h + 2*PLANE;
  ushort* v_pair = hm_l;
  ushort* xp_h  = hm_h;
  ushort* xp_l  = hm_h + PLANE;
  ushort* pem_h = hm_l;
  ushort* pem_l = hm_l + (size_t)2048*128;

  // grid sizes for swizzled gemm_h3: 8 * ceil(NT/8) * 32
  auto g3grid = [](int N){ int NT = N >> 7; return 8*((NT+7)/8)*32; };

  // patch embed
  k_patchify<<<6144, 256, 0, stream>>>(x, xp_h, xp_l);
  k_wsplit2h<<<dim3(2, 12, 1), 256, 0, stream>>>(pe1_w, aph, apl, 768, 128);
  gemm_h3<2><<<g3grid(128), 256, 0, stream>>>(xp_h, xp_l, aph, apl, nullptr, pem_h, pem_l, nullptr, 128, 768, pe1_b, nullptr, 0);
  k_wsplit2h<<<dim3(12, 2, 1), 256, 0, stream>>>(pe2_w, aph, apl, 128, 768);
  gemm_h3<1><<<g3grid(768), 256, 0, stream>>>(pem_h, pem_l, aph, apl, xbuf, nullptr, nullptr, nullptr, 768, 128, pe2_b, nullptr, 0);
  // conditioning
  k_cond<<<8, 256, 0, stream>>>(t, task_id, mod_id, t1_w, t1_b, t2_w, t2_b, task_tab, mod_tab, cbuf);

  for (int l = 0; l < 4; l++){
    k_mod<<<dim3(18, 8), 256, 0, stream>>>(cbuf, ada_w + (size_t)l*768*4608, ada_b + (size_t)l*4608, mod, 4608);
    // attention branch
    k_rms_mod<<<2048, 256, 0, stream>>>(xbuf, hh_h, hh_l, n1_w + l*768, mod + 0, mod + 768, 4608);
    k_wsplit2h<<<dim3(36, 12, 1), 256, 0, stream>>>(qkv_w + (size_t)l*768*2304, aqh, aql, 768, 2304);
    gemm_h3<4><<<g3grid(2304), 256, 0, stream>>>(hh_h, hh_l, aqh, aql, nullptr, q_pair, k_pair, v_pair, 2304, 768, nullptr, nullptr, 0);
    k_qkv_prep<<<2048, 256, 0, stream>>>(q_pair, k_pair, qn_w + l*64, kn_w + l*64);
    k_vtrans<<<96, 256, 0, stream>>>(v_pair, vt16);
    k_fattn<<<dim3(4, 96), 256, 0, stream>>>(q_pair, k_pair, vt16, attn_h, attn_l);
    k_wsplit2h<<<dim3(12, 12, 1), 256, 0, stream>>>(proj_w + (size_t)l*768*768, aph, apl, 768, 768);
    gemm_h3<3><<<g3grid(768), 256, 0, stream>>>(attn_h, attn_l, aph, apl, xbuf, nullptr, nullptr, nullptr, 768, 768, nullptr, mod + 2*768, 4608);
    // MoE branch
    k_rms_mod<<<2048, 256, 0, stream>>>(xbuf, hh_h, hh_l, n2_w + l*768, mod + 3*768, mod + 4*768, 4608);
    hipMemsetAsync(counts, 0, 8*sizeof(int), stream);
    k_router<<<512, 256, 0, stream>>>(hh_h, hh_l, rt_w + (size_t)l*768*8, counts, list, gate_slot);
    for (int g = 0; g < 8; g += G){
      k_wsplit2h<<<dim3(32, 12, G), 256, 0, stream>>>(w1 + ((size_t)(l*8 + g))*768*2048, aw1h, aw1l, 768, 2048);
      k_wsplit2h<<<dim3(32, 12, G), 256, 0, stream>>>(w3 + ((size_t)(l*8 + g))*768*2048, aw3h, aw3l, 768, 2048);
      int npan1 = G*16;
      moe_gemm1_h3<<<8*((npan1+7)/8)*32, 256, 0, stream>>>(hh_h, hh_l, aw1h, aw1l, aw3h, aw3l, counts, list, hm_h, hm_l, g, G);
    }
    for (int g = 0; g < 8; g += G){
      k_wsplit2h<<<dim3(12, 32, G), 256, 0, stream>>>(w2 + ((size_t)(l*8 + g))*2048*768, aw2h, aw2l, 2048, 768);
      int npan2 = G*6;
      moe_gemm2_h3<<<8*((npan2+7)/8)*32, 256, 0, stream>>>(hm_h, hm_l, aw2h, aw2l, counts, list, y_slot, gate_slot, g, G);
    }
    k_combine<<<6144, 256, 0, stream>>>(xbuf, y_slot, mod + 5*768);
  }

  // final layer
  k_mod<<<dim3(6, 8), 256, 0, stream>>>(cbuf, fada_w, fada_b, fmod, 1536);
  k_rms_mod<<<2048, 256, 0, stream>>>(xbuf, hh_h, hh_l, fn_w, fmod + 0, fmod + 768, 1536);
  k_wsplit2h<<<dim3(12, 12, 1), 256, 0, stream>>>(fp_w, aph, apl, 768, 768);
  gemm_h3<1><<<g3grid(768), 256, 0, stream>>>(hh_h, hh_l, aph, apl, (float*)d_out, nullptr, nullptr, nullptr, 768, 768, fp_b, nullptr, 0);
}